// Round 7
// baseline (1664.482 us; speedup 1.0000x reference)
//
#include <hip/hip_runtime.h>
#include <hip/hip_bf16.h>

// ED_Fourth_MOE round 7:
//  - conv: column-quad pixel remap + ALL 10 input-plane patches cached in registers
//    (f32x4 pq[10][3] + halo scalars, fully static indexing). conv1 does ZERO LDS
//    reads in the c-loop; conv2 LDS round-trip vectorized (b128). Per-pixel FMA
//    statement shapes/order verbatim round-1 (bit-exact tok; gating argmax fragile).
//    LDS 9.8KB, launch_bounds(256,2) for ~230 VGPR without spill.
//  - GEMM/gating/scatter/poly/loss: unchanged from round 6 (proven).

typedef __bf16 bf16x8 __attribute__((ext_vector_type(8)));
typedef __bf16 bf16x4 __attribute__((ext_vector_type(4)));
typedef __bf16 bf16x2 __attribute__((ext_vector_type(2)));
typedef float f32x4 __attribute__((ext_vector_type(4)));

#define NMOE 5
#define NEXP 4

// ---------------------------------------------------------------- conv fused
// One block per image, 256 threads: r = tid>>3 (row 0..31), cols c0..c0+3.
// LDS [34][36]: image row R -> idx R+1 (rows 0,33 zero halo); image col j -> idx j
// (0..31); col -1 -> idx 32 (zero); col 32 -> idx 33 (zero). 144B row stride keeps
// 16B alignment for any row.
__global__ __launch_bounds__(256, 2) void conv_tok_kernel(
    const float* __restrict__ input, const float* __restrict__ c1w,
    const float* __restrict__ c1b, const float* __restrict__ c2w,
    const float* __restrict__ c2b, float* __restrict__ tok_f32,
    __bf16* __restrict__ tok_bf16)
{
    __shared__ float S[34][36];
    __shared__ float P[34][36];
    const int b = blockIdx.x, tid = threadIdx.x;
    const int r = tid >> 3;
    const int c0 = (tid & 7) * 4;

    for (int i = tid; i < 34 * 36; i += 256) {
        (&S[0][0])[i] = 0.f;
        (&P[0][0])[i] = 0.f;
    }
    __syncthreads();

    const float* ip = input + (size_t)b * 10240;
    const int li = (c0 == 0) ? 32 : (c0 - 1);
    const int ri = (c0 == 28) ? 33 : (c0 + 4);

    // ---- stage each plane once, cache this thread's 3x6 patch in registers
    f32x4 pq[10][3];
    float pl[10][3], pr[10][3];
    #pragma unroll
    for (int ts = 0; ts < 10; ++ts) {
        if (ts > 0) __syncthreads();          // prior patch reads done before overwrite
        *(f32x4*)&S[r + 1][c0] = *(const f32x4*)(ip + ts * 1024 + tid * 4);
        __syncthreads();
        #pragma unroll
        for (int i = 0; i < 3; ++i) {
            pq[ts][i] = *(const f32x4*)&S[r + i][c0];
            pl[ts][i] = S[r + i][li];
            pr[ts][i] = S[r + i][ri];
        }
    }

    const float c2bias = c2b[0];
    float tk0 = c2bias, tk1 = c2bias, tk2 = c2bias, tk3 = c2bias;

    for (int c = 0; c < 10; ++c) {
        float w1l[27];
        #pragma unroll
        for (int i = 0; i < 27; ++i) w1l[i] = c1w[c * 27 + i];
        const float c1bias = c1b[c];

        #pragma unroll
        for (int t = 0; t < 10; ++t) {
            float a0 = c1bias, a1 = c1bias, a2 = c1bias, a3 = c1bias;
            #pragma unroll
            for (int dt = 0; dt < 3; ++dt) {
                const int ts = t + dt - 1;
                if (ts < 0 || ts > 9) continue;
                #pragma unroll
                for (int dw = 0; dw < 3; ++dw) {
                    const float u0 = w1l[dt * 9 + 0 + dw];
                    const float u1 = w1l[dt * 9 + 3 + dw];
                    const float u2 = w1l[dt * 9 + 6 + dw];
                    // CV(i, cidx): patch value at dh-row i, col offset cidx (-1..4)
#define CV(i, cidx) ((cidx) < 0 ? pl[ts][i] : ((cidx) > 3 ? pr[ts][i] : pq[ts][i][(cidx)]))
                    a0 += u0 * CV(0, dw - 1) + u1 * CV(1, dw - 1) + u2 * CV(2, dw - 1);
                    a1 += u0 * CV(0, dw + 0) + u1 * CV(1, dw + 0) + u2 * CV(2, dw + 0);
                    a2 += u0 * CV(0, dw + 1) + u1 * CV(1, dw + 1) + u2 * CV(2, dw + 1);
                    a3 += u0 * CV(0, dw + 2) + u1 * CV(1, dw + 2) + u2 * CV(2, dw + 2);
#undef CV
                }
            }
            __syncthreads();                  // previous (c,t) conv2 reads done
            f32x4 o = {fmaxf(a0, 0.f), fmaxf(a1, 0.f), fmaxf(a2, 0.f), fmaxf(a3, 0.f)};
            *(f32x4*)&P[r + 1][c0] = o;
            __syncthreads();
            const int wb = (c * 10 + t) * 9;
            f32x4 q[3]; float ql[3], qr[3];
            #pragma unroll
            for (int i = 0; i < 3; ++i) {
                q[i] = *(const f32x4*)&P[r + i][c0];
                ql[i] = P[r + i][li];
                qr[i] = P[r + i][ri];
            }
            #pragma unroll
            for (int dw = 0; dw < 3; ++dw) {
                const float u0 = c2w[wb + 0 + dw];
                const float u1 = c2w[wb + 3 + dw];
                const float u2 = c2w[wb + 6 + dw];
#define QV(i, cidx) ((cidx) < 0 ? ql[i] : ((cidx) > 3 ? qr[i] : q[i][(cidx)]))
                tk0 += u0 * QV(0, dw - 1) + u1 * QV(1, dw - 1) + u2 * QV(2, dw - 1);
                tk1 += u0 * QV(0, dw + 0) + u1 * QV(1, dw + 0) + u2 * QV(2, dw + 0);
                tk2 += u0 * QV(0, dw + 1) + u1 * QV(1, dw + 1) + u2 * QV(2, dw + 1);
                tk3 += u0 * QV(0, dw + 2) + u1 * QV(1, dw + 2) + u2 * QV(2, dw + 2);
#undef QV
            }
        }
    }
    float o0 = fmaxf(tk0, 0.f), o1 = fmaxf(tk1, 0.f);
    float o2 = fmaxf(tk2, 0.f), o3 = fmaxf(tk3, 0.f);
    size_t base = (size_t)b * 1024 + (size_t)r * 32 + c0;   // token = r*32 + col
    *(f32x4*)(tok_f32 + base) = f32x4{o0, o1, o2, o3};
    bf16x4 ob = {(__bf16)o0, (__bf16)o1, (__bf16)o2, (__bf16)o3};
    *(bf16x4*)(tok_bf16 + base) = ob;
}

// ---------------------------------------------------------------- gating
__global__ __launch_bounds__(256) void gating_kernel(
    const float* __restrict__ tok, const float* __restrict__ w_gate,
    int* __restrict__ expert_id, int* __restrict__ counts)
{
    int gw = blockIdx.x * 4 + (threadIdx.x >> 6);
    int l = threadIdx.x & 63;
    int n = gw >> 10, b = gw & 1023;
    const float* trow = tok + (size_t)b * 1024;
    const float* wg = w_gate + (size_t)n * 4096;
    float a0 = 0.f, a1 = 0.f, a2 = 0.f, a3 = 0.f;
    #pragma unroll
    for (int i = 0; i < 16; ++i) {
        int d = i * 64 + l;
        float tv = trow[d];
        float4 g4 = *(const float4*)(wg + d * 4);
        a0 += tv * g4.x; a1 += tv * g4.y; a2 += tv * g4.z; a3 += tv * g4.w;
    }
    #pragma unroll
    for (int off = 32; off >= 1; off >>= 1) {
        a0 += __shfl_xor(a0, off);
        a1 += __shfl_xor(a1, off);
        a2 += __shfl_xor(a2, off);
        a3 += __shfl_xor(a3, off);
    }
    if (l == 0) {
        int e = 0; float best = a0;
        if (a1 > best) { best = a1; e = 1; }
        if (a2 > best) { best = a2; e = 2; }
        if (a3 > best) { best = a3; e = 3; }
        expert_id[n * 1024 + b] = e;
        atomicAdd(&counts[n * 4 + e], 1);
    }
}

// ---------------------------------------------------------------- scatter
__global__ __launch_bounds__(1024) void scatter_kernel(
    const int* __restrict__ expert_id, const int* __restrict__ counts,
    int* __restrict__ row_base, int* __restrict__ rows)
{
    __shared__ int cur[4];
    int n = blockIdx.x, tid = threadIdx.x;
    if (tid == 0) {
        int c0 = counts[n * 4 + 0], c1 = counts[n * 4 + 1], c2 = counts[n * 4 + 2];
        cur[0] = 0; cur[1] = c0; cur[2] = c0 + c1; cur[3] = c0 + c1 + c2;
        row_base[n * 4 + 0] = cur[0]; row_base[n * 4 + 1] = cur[1];
        row_base[n * 4 + 2] = cur[2]; row_base[n * 4 + 3] = cur[3];
    }
    __syncthreads();
    int e = expert_id[n * 1024 + tid];
    int pos = atomicAdd(&cur[e], 1);
    rows[n * 1024 + pos] = tid;
}

// ---------------------------------------------------------------- grouped GEMM (BM=256, BN templated)
template <int K, int N, int BN, bool GATHER, bool RELU, bool OUTBF>
__global__ __launch_bounds__(512) void moe_gemm_kernel(
    const __bf16* __restrict__ Abase, const float* __restrict__ Bsrc,
    const float* __restrict__ bias, const int* __restrict__ rows_all,
    const int* __restrict__ counts_all, const int* __restrict__ rowbase_all,
    __bf16* __restrict__ outB, float* __restrict__ outF)
{
    constexpr int CQ  = BN / 4;
    constexpr int UB  = BN / 64;
    constexpr int NFR = BN / 32;

    const int gy = blockIdx.y;
    const int mod = gy >> 4, rem = gy & 15;
    const int e = rem >> 2, mt = rem & 3;
    const int grp = mod * 4 + e;
    const int cnt = counts_all[grp];
    const int row0 = mt * 256;
    if (row0 >= cnt) return;
    const int rbase = rowbase_all[grp];
    const int valid = min(256, cnt - row0);
    const int n0 = blockIdx.x * BN;
    const int* rows = rows_all + mod * 1024;

    __shared__ alignas(16) __bf16 As[256 * 64];
    __shared__ alignas(16) __bf16 Bs[BN * 64];

    const int tid = threadIdx.x;
    const int l = tid & 63, w = tid >> 6;
    const int wr = w >> 1, wc = w & 1;

    const __bf16* aptr[4];
    int woffA[4];
    const __bf16* abase2 = GATHER ? Abase : (Abase + (size_t)mod * 1024 * (size_t)K);
    #pragma unroll
    for (int i = 0; i < 4; ++i) {
        int flat = tid + i * 512;
        int rr = flat >> 3, cc = flat & 7;
        int ri = rbase + row0 + min(rr, valid - 1);
        int ga = GATHER ? rows[ri] : ri;
        aptr[i] = abase2 + (size_t)ga * K + cc * 8;
        woffA[i] = rr * 64 + ((cc ^ (rr & 7)) * 8);
    }
    const float* bp0 = Bsrc + (size_t)grp * K * N + n0;
    const float* bptr[UB][2];
    int boff[UB], bx[UB];
    #pragma unroll
    for (int i = 0; i < UB; ++i) {
        int u = tid + i * 512;
        int rp = u / CQ, cq = u % CQ;
        bptr[i][0] = bp0 + (size_t)(2 * rp) * N + 4 * cq;
        bptr[i][1] = bp0 + (size_t)(2 * rp + 1) * N + 4 * cq;
        boff[i] = (4 * cq) * 64 + ((rp & 3) << 1);
        bx[i] = (rp >> 2) ^ (4 * (cq & 1)) ^ ((cq >> 1) & 7);
    }

    f32x4 acc[4][NFR];
    f32x4 zero = {0.f, 0.f, 0.f, 0.f};
    #pragma unroll
    for (int mi = 0; mi < 4; ++mi)
        #pragma unroll
        for (int ni = 0; ni < NFR; ++ni) acc[mi][ni] = zero;

    bf16x8 av[4], avn[4];
    f32x4 bv[UB][2], bvn[UB][2];
    #pragma unroll
    for (int i = 0; i < 4; ++i) av[i] = *(const bf16x8*)aptr[i];
    #pragma unroll
    for (int i = 0; i < UB; ++i) {
        bv[i][0] = *(const f32x4*)bptr[i][0];
        bv[i][1] = *(const f32x4*)bptr[i][1];
    }

    for (int k0 = 0; k0 < K; k0 += 64) {
        __syncthreads();
        #pragma unroll
        for (int i = 0; i < 4; ++i) *(bf16x8*)(As + woffA[i]) = av[i];
        #pragma unroll
        for (int i = 0; i < UB; ++i) {
            #pragma unroll
            for (int qq = 0; qq < 4; ++qq) {
                bf16x2 val = {(__bf16)bv[i][0][qq], (__bf16)bv[i][1][qq]};
                *(bf16x2*)(Bs + boff[i] + qq * 64 + ((bx[i] ^ qq) << 3)) = val;
            }
        }
        if (k0 + 64 < K) {
            #pragma unroll
            for (int i = 0; i < 4; ++i) {
                aptr[i] += 64;
                avn[i] = *(const bf16x8*)aptr[i];
            }
            #pragma unroll
            for (int i = 0; i < UB; ++i) {
                bptr[i][0] += (size_t)64 * N;
                bptr[i][1] += (size_t)64 * N;
                bvn[i][0] = *(const f32x4*)bptr[i][0];
                bvn[i][1] = *(const f32x4*)bptr[i][1];
            }
        }
        __syncthreads();
        #pragma unroll
        for (int kk = 0; kk < 2; ++kk) {
            bf16x8 af[4], bfv[NFR];
            #pragma unroll
            for (int mi = 0; mi < 4; ++mi) {
                int row = wr * 64 + mi * 16 + (l & 15);
                int cc = (kk * 4 + (l >> 4)) ^ (row & 7);
                af[mi] = *(const bf16x8*)(As + row * 64 + cc * 8);
            }
            #pragma unroll
            for (int ni = 0; ni < NFR; ++ni) {
                int nrow = wc * (BN / 2) + ni * 16 + (l & 15);
                int gg = (nrow ^ (nrow >> 3)) & 7;
                int cc = (kk * 4 + (l >> 4)) ^ gg;
                bfv[ni] = *(const bf16x8*)(Bs + nrow * 64 + cc * 8);
            }
            #pragma unroll
            for (int mi = 0; mi < 4; ++mi)
                #pragma unroll
                for (int ni = 0; ni < NFR; ++ni)
                    acc[mi][ni] = __builtin_amdgcn_mfma_f32_16x16x32_bf16(
                        af[mi], bfv[ni], acc[mi][ni], 0, 0, 0);
        }
        #pragma unroll
        for (int i = 0; i < 4; ++i) av[i] = avn[i];
        #pragma unroll
        for (int i = 0; i < UB; ++i) {
            bv[i][0] = bvn[i][0];
            bv[i][1] = bvn[i][1];
        }
    }

    const int lrow = l >> 4, lcol = l & 15;
    #pragma unroll
    for (int ni = 0; ni < NFR; ++ni) {
        int col = n0 + wc * (BN / 2) + ni * 16 + lcol;
        float bval = bias[(size_t)grp * N + col];
        #pragma unroll
        for (int mi = 0; mi < 4; ++mi) {
            #pragma unroll
            for (int j = 0; j < 4; ++j) {
                int rt = wr * 64 + mi * 16 + lrow * 4 + j;
                if (rt < valid) {
                    float v = acc[mi][ni][j] + bval;
                    if (RELU) v = fmaxf(v, 0.f);
                    int crow = rbase + row0 + rt;
                    if (OUTBF) {
                        outB[((size_t)mod * 1024 + crow) * N + col] = (__bf16)v;
                    } else {
                        int tokid = rows[crow];
                        outF[((size_t)mod * 1024 + tokid) * N + col] = v;
                    }
                }
            }
        }
    }
}

// ---------------------------------------------------------------- poly + sigmoid
__global__ __launch_bounds__(256) void poly_kernel(
    const float* __restrict__ input, const float* __restrict__ moe,
    float* __restrict__ out)
{
    const int b = blockIdx.x, tid = threadIdx.x;
    float4 f0 = *(const float4*)(moe + (size_t)(0 * 1024 + b) * 1024 + tid * 4); // transform
    float4 f1 = *(const float4*)(moe + (size_t)(1 * 1024 + b) * 1024 + tid * 4); // add
    float4 f2 = *(const float4*)(moe + (size_t)(2 * 1024 + b) * 1024 + tid * 4); // quad
    float4 f3 = *(const float4*)(moe + (size_t)(3 * 1024 + b) * 1024 + tid * 4); // cubic
    float4 f4 = *(const float4*)(moe + (size_t)(4 * 1024 + b) * 1024 + tid * 4); // fourth
    const float4* ipv = (const float4*)(input + (size_t)b * 10240);
    float4* opv = (float4*)(out + (size_t)b * 10240);
    #pragma unroll
    for (int t = 0; t < 10; ++t) {
        float4 x = ipv[t * 256 + tid];
        float4 r;
        {
            float i2 = x.x * x.x;
            float p = i2 * (i2 * f4.x + x.x * f3.x + f2.x) + x.x * f0.x + f1.x;
            r.x = 1.f / (1.f + __expf(-p));
        }
        {
            float i2 = x.y * x.y;
            float p = i2 * (i2 * f4.y + x.y * f3.y + f2.y) + x.y * f0.y + f1.y;
            r.y = 1.f / (1.f + __expf(-p));
        }
        {
            float i2 = x.z * x.z;
            float p = i2 * (i2 * f4.z + x.z * f3.z + f2.z) + x.z * f0.z + f1.z;
            r.z = 1.f / (1.f + __expf(-p));
        }
        {
            float i2 = x.w * x.w;
            float p = i2 * (i2 * f4.w + x.w * f3.w + f2.w) + x.w * f0.w + f1.w;
            r.w = 1.f / (1.f + __expf(-p));
        }
        opv[t * 256 + tid] = r;
    }
}

// ---------------------------------------------------------------- loss
__global__ void loss_kernel(const int* __restrict__ counts, float* __restrict__ out_loss)
{
    if (threadIdx.x == 0 && blockIdx.x == 0) {
        float total = 0.f;
        for (int n = 0; n < NMOE; ++n) {
            const float m = 256.f;
            float var = 0.f;
            for (int e = 0; e < 4; ++e) {
                float d = (float)counts[n * 4 + e] - m;
                var += d * d;
            }
            var *= (1.f / 3.f);                       // ddof=1
            float cv2 = var / (m * m + 1e-10f);
            total += 2.f * cv2 * 1e-2f;               // importance == load == counts
        }
        *out_loss = total;
    }
}

// ---------------------------------------------------------------- launch
extern "C" void kernel_launch(void* const* d_in, const int* in_sizes, int n_in,
                              void* d_out, int out_size, void* d_ws, size_t ws_size,
                              hipStream_t stream)
{
    (void)in_sizes; (void)n_in; (void)out_size; (void)ws_size;
    const float* input = (const float*)d_in[0];
    const float* c1w   = (const float*)d_in[1];
    const float* c1b   = (const float*)d_in[2];
    const float* c2w   = (const float*)d_in[3];
    const float* c2b   = (const float*)d_in[4];
    const float* wgate = (const float*)d_in[5];
    const float* w1    = (const float*)d_in[6];
    const float* b1    = (const float*)d_in[7];
    const float* w2    = (const float*)d_in[8];
    const float* b2    = (const float*)d_in[9];
    float* out = (float*)d_out;

    char* ws = (char*)d_ws;
    float*  tok_f32   = (float*)(ws + 0);                 //  4 MB
    __bf16* tok_bf16  = (__bf16*)(ws + 4194304);          //  2 MB
    __bf16* h         = (__bf16*)(ws + 6291456);          // 20.97 MB [5][1024][2048] bf16
    float*  moe_out   = (float*)(ws + 27262976);          // 20.97 MB [5][1024][1024] f32
    int*    rows      = (int*)(ws + 48234496);            // [5][1024]
    int*    expert_id = (int*)(ws + 48254976);            // [5][1024]
    int*    counts    = (int*)(ws + 48275456);            // [5][4]
    int*    row_base  = (int*)(ws + 48275536);            // [5][4]

    hipMemsetAsync(counts, 0, NMOE * NEXP * sizeof(int), stream);

    conv_tok_kernel<<<1024, 256, 0, stream>>>(input, c1w, c1b, c2w, c2b, tok_f32, tok_bf16);
    gating_kernel<<<1280, 256, 0, stream>>>(tok_f32, wgate, expert_id, counts);
    scatter_kernel<<<5, 1024, 0, stream>>>(expert_id, counts, row_base, rows);

    moe_gemm_kernel<1024, 2048, 128, true, true, true><<<dim3(16, 80), 512, 0, stream>>>(
        tok_bf16, w1, b1, rows, counts, row_base, h, nullptr);
    moe_gemm_kernel<2048, 1024, 64, false, false, false><<<dim3(16, 80), 512, 0, stream>>>(
        h, w2, b2, rows, counts, row_base, nullptr, moe_out);

    poly_kernel<<<1024, 256, 0, stream>>>(input, moe_out, out);
    loss_kernel<<<1, 64, 0, stream>>>(counts, out + 10485760);
}

// Round 8
// 572.587 us; speedup vs baseline: 2.9069x; 2.9069x over previous
//
#include <hip/hip_runtime.h>
#include <hip/hip_bf16.h>

// ED_Fourth_MOE round 8:
//  - conv: round-7's proven-bit-exact statements + pixel remap (1 row x 4 cols/thread),
//    but LDS-resident planes (no giant reg cache — round-7 spilled 2.9GB to scratch).
//    All 10 planes staged once in S[10][33][36] (shared zero-halo row, 52.3KB w/ P ->
//    3 blocks/CU). Patches read as 2xb128 + 6 scalars; own-row quad cached in regs
//    (40 VGPR, static). conv1 t-amortized (round-5 proven ordering). conv2 reuses
//    own quad from the just-computed register value.
//  - GEMM/gating/scatter/poly/loss: unchanged (proven).

typedef __bf16 bf16x8 __attribute__((ext_vector_type(8)));
typedef __bf16 bf16x4 __attribute__((ext_vector_type(4)));
typedef __bf16 bf16x2 __attribute__((ext_vector_type(2)));
typedef float f32x4 __attribute__((ext_vector_type(4)));

#define NMOE 5
#define NEXP 4

// ---------------------------------------------------------------- conv fused
// LDS rows: idx 0 = shared zero halo (image rows -1 and 32); image row R -> idx R+1.
// LDS cols: image col j -> idx j (0..31); idx 32 = idx 33 = zero col halo; 34,35 pad.
// Row stride 36 floats = 144B (16B multiple) -> aligned b128 at any row.
__global__ __launch_bounds__(256, 3) void conv_tok_kernel(
    const float* __restrict__ input, const float* __restrict__ c1w,
    const float* __restrict__ c1b, const float* __restrict__ c2w,
    const float* __restrict__ c2b, float* __restrict__ tok_f32,
    __bf16* __restrict__ tok_bf16)
{
    __shared__ float S[10][33][36];   // 47520 B
    __shared__ float P[33][36];       //  4752 B
    const int b = blockIdx.x, tid = threadIdx.x;
    const int r = tid >> 3;           // pixel row 0..31
    const int c0 = (tid & 7) * 4;     // pixel col base

    for (int i = tid; i < 10 * 33 * 36; i += 256) (&S[0][0][0])[i] = 0.f;
    for (int i = tid; i < 33 * 36; i += 256) (&P[0][0])[i] = 0.f;
    __syncthreads();

    const float* ip = input + (size_t)b * 10240;
    const int rB = r + 1;                         // own row idx
    const int rA = r;                             // image row r-1 (r=0 -> zero row)
    const int rC = (r == 31) ? 0 : (r + 2);       // image row r+1 (r=31 -> zero row)
    const int li  = (c0 == 0) ? 32 : (c0 - 1);
    const int rix = (c0 == 28) ? 33 : (c0 + 4);

    // stage all planes once; keep own-row quad in registers
    f32x4 own[10];
    #pragma unroll
    for (int ts = 0; ts < 10; ++ts) {
        f32x4 v = *(const f32x4*)(ip + ts * 1024 + tid * 4);
        *(f32x4*)&S[ts][rB][c0] = v;
        own[ts] = v;
    }
    __syncthreads();

    const float c2bias = c2b[0];
    float tk0 = c2bias, tk1 = c2bias, tk2 = c2bias, tk3 = c2bias;

    for (int c = 0; c < 10; ++c) {
        float w1l[27];
        #pragma unroll
        for (int i = 0; i < 27; ++i) w1l[i] = c1w[c * 27 + i];
        const float c1bias = c1b[c];

        float a0[10], a1[10], a2[10], a3[10];
        #pragma unroll
        for (int t = 0; t < 10; ++t) {
            a0[t] = c1bias; a1[t] = c1bias; a2[t] = c1bias; a3[t] = c1bias;
        }

        #pragma unroll
        for (int ts = 0; ts < 10; ++ts) {
            // ---- vectorized patch of plane ts (own row from regs)
            f32x4 qA = *(const f32x4*)&S[ts][rA][c0];
            f32x4 qC = *(const f32x4*)&S[ts][rC][c0];
            const f32x4 qB = own[ts];
            float lA = S[ts][rA][li], hA = S[ts][rA][rix];
            float lB = S[ts][rB][li], hB = S[ts][rB][rix];
            float lC = S[ts][rC][li], hC = S[ts][rC][rix];

            // plane ts feeds acc[ts+1] (dt=0), acc[ts] (dt=1), acc[ts-1] (dt=2);
            // as ts ascends each acc[t] receives dt=0,1,2 ascending == round-1 order.
            #pragma unroll
            for (int dt = 0; dt < 3; ++dt) {
                const int t = ts - dt + 1;
                if (t < 0 || t > 9) continue;
                #pragma unroll
                for (int dw = 0; dw < 3; ++dw) {
                    const float u0 = w1l[dt * 9 + 0 + dw];
                    const float u1 = w1l[dt * 9 + 3 + dw];
                    const float u2 = w1l[dt * 9 + 6 + dw];
#define CV0(cidx) ((cidx) < 0 ? lA : ((cidx) > 3 ? hA : qA[(cidx)]))
#define CV1(cidx) ((cidx) < 0 ? lB : ((cidx) > 3 ? hB : qB[(cidx)]))
#define CV2(cidx) ((cidx) < 0 ? lC : ((cidx) > 3 ? hC : qC[(cidx)]))
                    a0[t] += u0 * CV0(dw - 1) + u1 * CV1(dw - 1) + u2 * CV2(dw - 1);
                    a1[t] += u0 * CV0(dw + 0) + u1 * CV1(dw + 0) + u2 * CV2(dw + 0);
                    a2[t] += u0 * CV0(dw + 1) + u1 * CV1(dw + 1) + u2 * CV2(dw + 1);
                    a3[t] += u0 * CV0(dw + 2) + u1 * CV1(dw + 2) + u2 * CV2(dw + 2);
#undef CV0
#undef CV1
#undef CV2
                }
            }

            // ---- acc[ts-1] complete: P round-trip + conv2 (round-7 verbatim forms)
            if (ts >= 1) {
                const int td = ts - 1;
                __syncthreads();              // previous (c,t) conv2 reads done
                f32x4 o = {fmaxf(a0[td], 0.f), fmaxf(a1[td], 0.f),
                           fmaxf(a2[td], 0.f), fmaxf(a3[td], 0.f)};
                *(f32x4*)&P[rB][c0] = o;
                __syncthreads();
                const int wb = (c * 10 + td) * 9;
                f32x4 sA = *(const f32x4*)&P[rA][c0];
                f32x4 sC = *(const f32x4*)&P[rC][c0];
                const f32x4 sB = o;
                float mlA = P[rA][li], mhA = P[rA][rix];
                float mlB = P[rB][li], mhB = P[rB][rix];
                float mlC = P[rC][li], mhC = P[rC][rix];
                #pragma unroll
                for (int dw = 0; dw < 3; ++dw) {
                    const float u0 = c2w[wb + 0 + dw];
                    const float u1 = c2w[wb + 3 + dw];
                    const float u2 = c2w[wb + 6 + dw];
#define QV0(cidx) ((cidx) < 0 ? mlA : ((cidx) > 3 ? mhA : sA[(cidx)]))
#define QV1(cidx) ((cidx) < 0 ? mlB : ((cidx) > 3 ? mhB : sB[(cidx)]))
#define QV2(cidx) ((cidx) < 0 ? mlC : ((cidx) > 3 ? mhC : sC[(cidx)]))
                    tk0 += u0 * QV0(dw - 1) + u1 * QV1(dw - 1) + u2 * QV2(dw - 1);
                    tk1 += u0 * QV0(dw + 0) + u1 * QV1(dw + 0) + u2 * QV2(dw + 0);
                    tk2 += u0 * QV0(dw + 1) + u1 * QV1(dw + 1) + u2 * QV2(dw + 1);
                    tk3 += u0 * QV0(dw + 2) + u1 * QV1(dw + 2) + u2 * QV2(dw + 2);
#undef QV0
#undef QV1
#undef QV2
                }
            }
        }
        // ---- tail: td = 9
        {
            __syncthreads();
            f32x4 o = {fmaxf(a0[9], 0.f), fmaxf(a1[9], 0.f),
                       fmaxf(a2[9], 0.f), fmaxf(a3[9], 0.f)};
            *(f32x4*)&P[rB][c0] = o;
            __syncthreads();
            const int wb = (c * 10 + 9) * 9;
            f32x4 sA = *(const f32x4*)&P[rA][c0];
            f32x4 sC = *(const f32x4*)&P[rC][c0];
            const f32x4 sB = o;
            float mlA = P[rA][li], mhA = P[rA][rix];
            float mlB = P[rB][li], mhB = P[rB][rix];
            float mlC = P[rC][li], mhC = P[rC][rix];
            #pragma unroll
            for (int dw = 0; dw < 3; ++dw) {
                const float u0 = c2w[wb + 0 + dw];
                const float u1 = c2w[wb + 3 + dw];
                const float u2 = c2w[wb + 6 + dw];
#define QV0(cidx) ((cidx) < 0 ? mlA : ((cidx) > 3 ? mhA : sA[(cidx)]))
#define QV1(cidx) ((cidx) < 0 ? mlB : ((cidx) > 3 ? mhB : sB[(cidx)]))
#define QV2(cidx) ((cidx) < 0 ? mlC : ((cidx) > 3 ? mhC : sC[(cidx)]))
                tk0 += u0 * QV0(dw - 1) + u1 * QV1(dw - 1) + u2 * QV2(dw - 1);
                tk1 += u0 * QV0(dw + 0) + u1 * QV1(dw + 0) + u2 * QV2(dw + 0);
                tk2 += u0 * QV0(dw + 1) + u1 * QV1(dw + 1) + u2 * QV2(dw + 1);
                tk3 += u0 * QV0(dw + 2) + u1 * QV1(dw + 2) + u2 * QV2(dw + 2);
#undef QV0
#undef QV1
#undef QV2
            }
        }
    }
    float o0 = fmaxf(tk0, 0.f), o1 = fmaxf(tk1, 0.f);
    float o2 = fmaxf(tk2, 0.f), o3 = fmaxf(tk3, 0.f);
    size_t base = (size_t)b * 1024 + (size_t)r * 32 + c0;
    *(f32x4*)(tok_f32 + base) = f32x4{o0, o1, o2, o3};
    bf16x4 ob = {(__bf16)o0, (__bf16)o1, (__bf16)o2, (__bf16)o3};
    *(bf16x4*)(tok_bf16 + base) = ob;
}

// ---------------------------------------------------------------- gating
__global__ __launch_bounds__(256) void gating_kernel(
    const float* __restrict__ tok, const float* __restrict__ w_gate,
    int* __restrict__ expert_id, int* __restrict__ counts)
{
    int gw = blockIdx.x * 4 + (threadIdx.x >> 6);
    int l = threadIdx.x & 63;
    int n = gw >> 10, b = gw & 1023;
    const float* trow = tok + (size_t)b * 1024;
    const float* wg = w_gate + (size_t)n * 4096;
    float a0 = 0.f, a1 = 0.f, a2 = 0.f, a3 = 0.f;
    #pragma unroll
    for (int i = 0; i < 16; ++i) {
        int d = i * 64 + l;
        float tv = trow[d];
        float4 g4 = *(const float4*)(wg + d * 4);
        a0 += tv * g4.x; a1 += tv * g4.y; a2 += tv * g4.z; a3 += tv * g4.w;
    }
    #pragma unroll
    for (int off = 32; off >= 1; off >>= 1) {
        a0 += __shfl_xor(a0, off);
        a1 += __shfl_xor(a1, off);
        a2 += __shfl_xor(a2, off);
        a3 += __shfl_xor(a3, off);
    }
    if (l == 0) {
        int e = 0; float best = a0;
        if (a1 > best) { best = a1; e = 1; }
        if (a2 > best) { best = a2; e = 2; }
        if (a3 > best) { best = a3; e = 3; }
        expert_id[n * 1024 + b] = e;
        atomicAdd(&counts[n * 4 + e], 1);
    }
}

// ---------------------------------------------------------------- scatter
__global__ __launch_bounds__(1024) void scatter_kernel(
    const int* __restrict__ expert_id, const int* __restrict__ counts,
    int* __restrict__ row_base, int* __restrict__ rows)
{
    __shared__ int cur[4];
    int n = blockIdx.x, tid = threadIdx.x;
    if (tid == 0) {
        int c0 = counts[n * 4 + 0], c1 = counts[n * 4 + 1], c2 = counts[n * 4 + 2];
        cur[0] = 0; cur[1] = c0; cur[2] = c0 + c1; cur[3] = c0 + c1 + c2;
        row_base[n * 4 + 0] = cur[0]; row_base[n * 4 + 1] = cur[1];
        row_base[n * 4 + 2] = cur[2]; row_base[n * 4 + 3] = cur[3];
    }
    __syncthreads();
    int e = expert_id[n * 1024 + tid];
    int pos = atomicAdd(&cur[e], 1);
    rows[n * 1024 + pos] = tid;
}

// ---------------------------------------------------------------- grouped GEMM (BM=256, BN templated)
template <int K, int N, int BN, bool GATHER, bool RELU, bool OUTBF>
__global__ __launch_bounds__(512) void moe_gemm_kernel(
    const __bf16* __restrict__ Abase, const float* __restrict__ Bsrc,
    const float* __restrict__ bias, const int* __restrict__ rows_all,
    const int* __restrict__ counts_all, const int* __restrict__ rowbase_all,
    __bf16* __restrict__ outB, float* __restrict__ outF)
{
    constexpr int CQ  = BN / 4;
    constexpr int UB  = BN / 64;
    constexpr int NFR = BN / 32;

    const int gy = blockIdx.y;
    const int mod = gy >> 4, rem = gy & 15;
    const int e = rem >> 2, mt = rem & 3;
    const int grp = mod * 4 + e;
    const int cnt = counts_all[grp];
    const int row0 = mt * 256;
    if (row0 >= cnt) return;
    const int rbase = rowbase_all[grp];
    const int valid = min(256, cnt - row0);
    const int n0 = blockIdx.x * BN;
    const int* rows = rows_all + mod * 1024;

    __shared__ alignas(16) __bf16 As[256 * 64];
    __shared__ alignas(16) __bf16 Bs[BN * 64];

    const int tid = threadIdx.x;
    const int l = tid & 63, w = tid >> 6;
    const int wr = w >> 1, wc = w & 1;

    const __bf16* aptr[4];
    int woffA[4];
    const __bf16* abase2 = GATHER ? Abase : (Abase + (size_t)mod * 1024 * (size_t)K);
    #pragma unroll
    for (int i = 0; i < 4; ++i) {
        int flat = tid + i * 512;
        int rr = flat >> 3, cc = flat & 7;
        int ri = rbase + row0 + min(rr, valid - 1);
        int ga = GATHER ? rows[ri] : ri;
        aptr[i] = abase2 + (size_t)ga * K + cc * 8;
        woffA[i] = rr * 64 + ((cc ^ (rr & 7)) * 8);
    }
    const float* bp0 = Bsrc + (size_t)grp * K * N + n0;
    const float* bptr[UB][2];
    int boff[UB], bx[UB];
    #pragma unroll
    for (int i = 0; i < UB; ++i) {
        int u = tid + i * 512;
        int rp = u / CQ, cq = u % CQ;
        bptr[i][0] = bp0 + (size_t)(2 * rp) * N + 4 * cq;
        bptr[i][1] = bp0 + (size_t)(2 * rp + 1) * N + 4 * cq;
        boff[i] = (4 * cq) * 64 + ((rp & 3) << 1);
        bx[i] = (rp >> 2) ^ (4 * (cq & 1)) ^ ((cq >> 1) & 7);
    }

    f32x4 acc[4][NFR];
    f32x4 zero = {0.f, 0.f, 0.f, 0.f};
    #pragma unroll
    for (int mi = 0; mi < 4; ++mi)
        #pragma unroll
        for (int ni = 0; ni < NFR; ++ni) acc[mi][ni] = zero;

    bf16x8 av[4], avn[4];
    f32x4 bv[UB][2], bvn[UB][2];
    #pragma unroll
    for (int i = 0; i < 4; ++i) av[i] = *(const bf16x8*)aptr[i];
    #pragma unroll
    for (int i = 0; i < UB; ++i) {
        bv[i][0] = *(const f32x4*)bptr[i][0];
        bv[i][1] = *(const f32x4*)bptr[i][1];
    }

    for (int k0 = 0; k0 < K; k0 += 64) {
        __syncthreads();
        #pragma unroll
        for (int i = 0; i < 4; ++i) *(bf16x8*)(As + woffA[i]) = av[i];
        #pragma unroll
        for (int i = 0; i < UB; ++i) {
            #pragma unroll
            for (int qq = 0; qq < 4; ++qq) {
                bf16x2 val = {(__bf16)bv[i][0][qq], (__bf16)bv[i][1][qq]};
                *(bf16x2*)(Bs + boff[i] + qq * 64 + ((bx[i] ^ qq) << 3)) = val;
            }
        }
        if (k0 + 64 < K) {
            #pragma unroll
            for (int i = 0; i < 4; ++i) {
                aptr[i] += 64;
                avn[i] = *(const bf16x8*)aptr[i];
            }
            #pragma unroll
            for (int i = 0; i < UB; ++i) {
                bptr[i][0] += (size_t)64 * N;
                bptr[i][1] += (size_t)64 * N;
                bvn[i][0] = *(const f32x4*)bptr[i][0];
                bvn[i][1] = *(const f32x4*)bptr[i][1];
            }
        }
        __syncthreads();
        #pragma unroll
        for (int kk = 0; kk < 2; ++kk) {
            bf16x8 af[4], bfv[NFR];
            #pragma unroll
            for (int mi = 0; mi < 4; ++mi) {
                int row = wr * 64 + mi * 16 + (l & 15);
                int cc = (kk * 4 + (l >> 4)) ^ (row & 7);
                af[mi] = *(const bf16x8*)(As + row * 64 + cc * 8);
            }
            #pragma unroll
            for (int ni = 0; ni < NFR; ++ni) {
                int nrow = wc * (BN / 2) + ni * 16 + (l & 15);
                int gg = (nrow ^ (nrow >> 3)) & 7;
                int cc = (kk * 4 + (l >> 4)) ^ gg;
                bfv[ni] = *(const bf16x8*)(Bs + nrow * 64 + cc * 8);
            }
            #pragma unroll
            for (int mi = 0; mi < 4; ++mi)
                #pragma unroll
                for (int ni = 0; ni < NFR; ++ni)
                    acc[mi][ni] = __builtin_amdgcn_mfma_f32_16x16x32_bf16(
                        af[mi], bfv[ni], acc[mi][ni], 0, 0, 0);
        }
        #pragma unroll
        for (int i = 0; i < 4; ++i) av[i] = avn[i];
        #pragma unroll
        for (int i = 0; i < UB; ++i) {
            bv[i][0] = bvn[i][0];
            bv[i][1] = bvn[i][1];
        }
    }

    const int lrow = l >> 4, lcol = l & 15;
    #pragma unroll
    for (int ni = 0; ni < NFR; ++ni) {
        int col = n0 + wc * (BN / 2) + ni * 16 + lcol;
        float bval = bias[(size_t)grp * N + col];
        #pragma unroll
        for (int mi = 0; mi < 4; ++mi) {
            #pragma unroll
            for (int j = 0; j < 4; ++j) {
                int rt = wr * 64 + mi * 16 + lrow * 4 + j;
                if (rt < valid) {
                    float v = acc[mi][ni][j] + bval;
                    if (RELU) v = fmaxf(v, 0.f);
                    int crow = rbase + row0 + rt;
                    if (OUTBF) {
                        outB[((size_t)mod * 1024 + crow) * N + col] = (__bf16)v;
                    } else {
                        int tokid = rows[crow];
                        outF[((size_t)mod * 1024 + tokid) * N + col] = v;
                    }
                }
            }
        }
    }
}

// ---------------------------------------------------------------- poly + sigmoid
__global__ __launch_bounds__(256) void poly_kernel(
    const float* __restrict__ input, const float* __restrict__ moe,
    float* __restrict__ out)
{
    const int b = blockIdx.x, tid = threadIdx.x;
    float4 f0 = *(const float4*)(moe + (size_t)(0 * 1024 + b) * 1024 + tid * 4); // transform
    float4 f1 = *(const float4*)(moe + (size_t)(1 * 1024 + b) * 1024 + tid * 4); // add
    float4 f2 = *(const float4*)(moe + (size_t)(2 * 1024 + b) * 1024 + tid * 4); // quad
    float4 f3 = *(const float4*)(moe + (size_t)(3 * 1024 + b) * 1024 + tid * 4); // cubic
    float4 f4 = *(const float4*)(moe + (size_t)(4 * 1024 + b) * 1024 + tid * 4); // fourth
    const float4* ipv = (const float4*)(input + (size_t)b * 10240);
    float4* opv = (float4*)(out + (size_t)b * 10240);
    #pragma unroll
    for (int t = 0; t < 10; ++t) {
        float4 x = ipv[t * 256 + tid];
        float4 r;
        {
            float i2 = x.x * x.x;
            float p = i2 * (i2 * f4.x + x.x * f3.x + f2.x) + x.x * f0.x + f1.x;
            r.x = 1.f / (1.f + __expf(-p));
        }
        {
            float i2 = x.y * x.y;
            float p = i2 * (i2 * f4.y + x.y * f3.y + f2.y) + x.y * f0.y + f1.y;
            r.y = 1.f / (1.f + __expf(-p));
        }
        {
            float i2 = x.z * x.z;
            float p = i2 * (i2 * f4.z + x.z * f3.z + f2.z) + x.z * f0.z + f1.z;
            r.z = 1.f / (1.f + __expf(-p));
        }
        {
            float i2 = x.w * x.w;
            float p = i2 * (i2 * f4.w + x.w * f3.w + f2.w) + x.w * f0.w + f1.w;
            r.w = 1.f / (1.f + __expf(-p));
        }
        opv[t * 256 + tid] = r;
    }
}

// ---------------------------------------------------------------- loss
__global__ void loss_kernel(const int* __restrict__ counts, float* __restrict__ out_loss)
{
    if (threadIdx.x == 0 && blockIdx.x == 0) {
        float total = 0.f;
        for (int n = 0; n < NMOE; ++n) {
            const float m = 256.f;
            float var = 0.f;
            for (int e = 0; e < 4; ++e) {
                float d = (float)counts[n * 4 + e] - m;
                var += d * d;
            }
            var *= (1.f / 3.f);                       // ddof=1
            float cv2 = var / (m * m + 1e-10f);
            total += 2.f * cv2 * 1e-2f;               // importance == load == counts
        }
        *out_loss = total;
    }
}

// ---------------------------------------------------------------- launch
extern "C" void kernel_launch(void* const* d_in, const int* in_sizes, int n_in,
                              void* d_out, int out_size, void* d_ws, size_t ws_size,
                              hipStream_t stream)
{
    (void)in_sizes; (void)n_in; (void)out_size; (void)ws_size;
    const float* input = (const float*)d_in[0];
    const float* c1w   = (const float*)d_in[1];
    const float* c1b   = (const float*)d_in[2];
    const float* c2w   = (const float*)d_in[3];
    const float* c2b   = (const float*)d_in[4];
    const float* wgate = (const float*)d_in[5];
    const float* w1    = (const float*)d_in[6];
    const float* b1    = (const float*)d_in[7];
    const float* w2    = (const float*)d_in[8];
    const float* b2    = (const float*)d_in[9];
    float* out = (float*)d_out;

    char* ws = (char*)d_ws;
    float*  tok_f32   = (float*)(ws + 0);                 //  4 MB
    __bf16* tok_bf16  = (__bf16*)(ws + 4194304);          //  2 MB
    __bf16* h         = (__bf16*)(ws + 6291456);          // 20.97 MB [5][1024][2048] bf16
    float*  moe_out   = (float*)(ws + 27262976);          // 20.97 MB [5][1024][1024] f32
    int*    rows      = (int*)(ws + 48234496);            // [5][1024]
    int*    expert_id = (int*)(ws + 48254976);            // [5][1024]
    int*    counts    = (int*)(ws + 48275456);            // [5][4]
    int*    row_base  = (int*)(ws + 48275536);            // [5][4]

    hipMemsetAsync(counts, 0, NMOE * NEXP * sizeof(int), stream);

    conv_tok_kernel<<<1024, 256, 0, stream>>>(input, c1w, c1b, c2w, c2b, tok_f32, tok_bf16);
    gating_kernel<<<1280, 256, 0, stream>>>(tok_f32, wgate, expert_id, counts);
    scatter_kernel<<<5, 1024, 0, stream>>>(expert_id, counts, row_base, rows);

    moe_gemm_kernel<1024, 2048, 128, true, true, true><<<dim3(16, 80), 512, 0, stream>>>(
        tok_bf16, w1, b1, rows, counts, row_base, h, nullptr);
    moe_gemm_kernel<2048, 1024, 64, false, false, false><<<dim3(16, 80), 512, 0, stream>>>(
        h, w2, b2, rows, counts, row_base, nullptr, moe_out);

    poly_kernel<<<1024, 256, 0, stream>>>(input, moe_out, out);
    loss_kernel<<<1, 64, 0, stream>>>(counts, out + 10485760);
}

// Round 9
// 522.876 us; speedup vs baseline: 3.1833x; 1.0951x over previous
//
#include <hip/hip_runtime.h>
#include <hip/hip_bf16.h>

// ED_Fourth_MOE round 9:
//  - conv: per-t scalar accumulators (NO register arrays -> no unroll/scratch hazard;
//    rounds 7-8 proved big reg arrays spill) + vectorized patch reads (3xb128 + 6
//    scalars) from all-planes-resident S[10][33][36] (round-8 staging, proven).
//    All FMA statement forms verbatim round-8 (bit-exact tok).
//  - GEMM/gating/scatter/poly/loss: unchanged (proven).

typedef __bf16 bf16x8 __attribute__((ext_vector_type(8)));
typedef __bf16 bf16x4 __attribute__((ext_vector_type(4)));
typedef __bf16 bf16x2 __attribute__((ext_vector_type(2)));
typedef float f32x4 __attribute__((ext_vector_type(4)));

#define NMOE 5
#define NEXP 4

// ---------------------------------------------------------------- conv fused
// LDS rows: idx 0 = shared zero halo (image rows -1 and 32); image row R -> idx R+1.
// LDS cols: image col j -> idx j (0..31); idx 32/33 = zero col halos; 34,35 pad.
// Row stride 36 floats = 144B (16B multiple) -> aligned b128 at any row.
__global__ __launch_bounds__(256, 3) void conv_tok_kernel(
    const float* __restrict__ input, const float* __restrict__ c1w,
    const float* __restrict__ c1b, const float* __restrict__ c2w,
    const float* __restrict__ c2b, float* __restrict__ tok_f32,
    __bf16* __restrict__ tok_bf16)
{
    __shared__ float S[10][33][36];   // 47520 B
    __shared__ float P[33][36];       //  4752 B
    const int b = blockIdx.x, tid = threadIdx.x;
    const int r = tid >> 3;           // pixel row 0..31
    const int c0 = (tid & 7) * 4;     // pixel col base

    for (int i = tid; i < 10 * 33 * 36; i += 256) (&S[0][0][0])[i] = 0.f;
    for (int i = tid; i < 33 * 36; i += 256) (&P[0][0])[i] = 0.f;
    __syncthreads();

    const float* ip = input + (size_t)b * 10240;
    const int rB = r + 1;                         // own row idx
    const int rA = r;                             // image row r-1 (r=0 -> zero row)
    const int rC = (r == 31) ? 0 : (r + 2);       // image row r+1 (r=31 -> zero row)
    const int li  = (c0 == 0) ? 32 : (c0 - 1);
    const int rix = (c0 == 28) ? 33 : (c0 + 4);

    // stage all planes once
    #pragma unroll
    for (int ts = 0; ts < 10; ++ts) {
        *(f32x4*)&S[ts][rB][c0] = *(const f32x4*)(ip + ts * 1024 + tid * 4);
    }
    __syncthreads();

    const float c2bias = c2b[0];
    float tk0 = c2bias, tk1 = c2bias, tk2 = c2bias, tk3 = c2bias;

    for (int c = 0; c < 10; ++c) {
        float w1l[27];
        #pragma unroll
        for (int i = 0; i < 27; ++i) w1l[i] = c1w[c * 27 + i];
        const float c1bias = c1b[c];

        for (int t = 0; t < 10; ++t) {
            float a0 = c1bias, a1 = c1bias, a2 = c1bias, a3 = c1bias;
            #pragma unroll
            for (int dt = 0; dt < 3; ++dt) {
                const int ts = t + dt - 1;
                if (ts < 0 || ts > 9) continue;
                // vectorized 3-row patch of plane ts
                f32x4 qA = *(const f32x4*)&S[ts][rA][c0];
                f32x4 qB = *(const f32x4*)&S[ts][rB][c0];
                f32x4 qC = *(const f32x4*)&S[ts][rC][c0];
                float lA = S[ts][rA][li], hA = S[ts][rA][rix];
                float lB = S[ts][rB][li], hB = S[ts][rB][rix];
                float lC = S[ts][rC][li], hC = S[ts][rC][rix];
                #pragma unroll
                for (int dw = 0; dw < 3; ++dw) {
                    const float u0 = w1l[dt * 9 + 0 + dw];
                    const float u1 = w1l[dt * 9 + 3 + dw];
                    const float u2 = w1l[dt * 9 + 6 + dw];
#define CV0(cidx) ((cidx) < 0 ? lA : ((cidx) > 3 ? hA : qA[(cidx)]))
#define CV1(cidx) ((cidx) < 0 ? lB : ((cidx) > 3 ? hB : qB[(cidx)]))
#define CV2(cidx) ((cidx) < 0 ? lC : ((cidx) > 3 ? hC : qC[(cidx)]))
                    a0 += u0 * CV0(dw - 1) + u1 * CV1(dw - 1) + u2 * CV2(dw - 1);
                    a1 += u0 * CV0(dw + 0) + u1 * CV1(dw + 0) + u2 * CV2(dw + 0);
                    a2 += u0 * CV0(dw + 1) + u1 * CV1(dw + 1) + u2 * CV2(dw + 1);
                    a3 += u0 * CV0(dw + 2) + u1 * CV1(dw + 2) + u2 * CV2(dw + 2);
#undef CV0
#undef CV1
#undef CV2
                }
            }

            __syncthreads();              // previous (c,t) conv2 reads done
            f32x4 o = {fmaxf(a0, 0.f), fmaxf(a1, 0.f), fmaxf(a2, 0.f), fmaxf(a3, 0.f)};
            *(f32x4*)&P[rB][c0] = o;
            __syncthreads();
            const int wb = (c * 10 + t) * 9;
            f32x4 sA = *(const f32x4*)&P[rA][c0];
            f32x4 sC = *(const f32x4*)&P[rC][c0];
            const f32x4 sB = o;
            float mlA = P[rA][li], mhA = P[rA][rix];
            float mlB = P[rB][li], mhB = P[rB][rix];
            float mlC = P[rC][li], mhC = P[rC][rix];
            #pragma unroll
            for (int dw = 0; dw < 3; ++dw) {
                const float u0 = c2w[wb + 0 + dw];
                const float u1 = c2w[wb + 3 + dw];
                const float u2 = c2w[wb + 6 + dw];
#define QV0(cidx) ((cidx) < 0 ? mlA : ((cidx) > 3 ? mhA : sA[(cidx)]))
#define QV1(cidx) ((cidx) < 0 ? mlB : ((cidx) > 3 ? mhB : sB[(cidx)]))
#define QV2(cidx) ((cidx) < 0 ? mlC : ((cidx) > 3 ? mhC : sC[(cidx)]))
                tk0 += u0 * QV0(dw - 1) + u1 * QV1(dw - 1) + u2 * QV2(dw - 1);
                tk1 += u0 * QV0(dw + 0) + u1 * QV1(dw + 0) + u2 * QV2(dw + 0);
                tk2 += u0 * QV0(dw + 1) + u1 * QV1(dw + 1) + u2 * QV2(dw + 1);
                tk3 += u0 * QV0(dw + 2) + u1 * QV1(dw + 2) + u2 * QV2(dw + 2);
#undef QV0
#undef QV1
#undef QV2
            }
        }
    }
    float o0 = fmaxf(tk0, 0.f), o1 = fmaxf(tk1, 0.f);
    float o2 = fmaxf(tk2, 0.f), o3 = fmaxf(tk3, 0.f);
    size_t base = (size_t)b * 1024 + (size_t)r * 32 + c0;
    *(f32x4*)(tok_f32 + base) = f32x4{o0, o1, o2, o3};
    bf16x4 ob = {(__bf16)o0, (__bf16)o1, (__bf16)o2, (__bf16)o3};
    *(bf16x4*)(tok_bf16 + base) = ob;
}

// ---------------------------------------------------------------- gating
__global__ __launch_bounds__(256) void gating_kernel(
    const float* __restrict__ tok, const float* __restrict__ w_gate,
    int* __restrict__ expert_id, int* __restrict__ counts)
{
    int gw = blockIdx.x * 4 + (threadIdx.x >> 6);
    int l = threadIdx.x & 63;
    int n = gw >> 10, b = gw & 1023;
    const float* trow = tok + (size_t)b * 1024;
    const float* wg = w_gate + (size_t)n * 4096;
    float a0 = 0.f, a1 = 0.f, a2 = 0.f, a3 = 0.f;
    #pragma unroll
    for (int i = 0; i < 16; ++i) {
        int d = i * 64 + l;
        float tv = trow[d];
        float4 g4 = *(const float4*)(wg + d * 4);
        a0 += tv * g4.x; a1 += tv * g4.y; a2 += tv * g4.z; a3 += tv * g4.w;
    }
    #pragma unroll
    for (int off = 32; off >= 1; off >>= 1) {
        a0 += __shfl_xor(a0, off);
        a1 += __shfl_xor(a1, off);
        a2 += __shfl_xor(a2, off);
        a3 += __shfl_xor(a3, off);
    }
    if (l == 0) {
        int e = 0; float best = a0;
        if (a1 > best) { best = a1; e = 1; }
        if (a2 > best) { best = a2; e = 2; }
        if (a3 > best) { best = a3; e = 3; }
        expert_id[n * 1024 + b] = e;
        atomicAdd(&counts[n * 4 + e], 1);
    }
}

// ---------------------------------------------------------------- scatter
__global__ __launch_bounds__(1024) void scatter_kernel(
    const int* __restrict__ expert_id, const int* __restrict__ counts,
    int* __restrict__ row_base, int* __restrict__ rows)
{
    __shared__ int cur[4];
    int n = blockIdx.x, tid = threadIdx.x;
    if (tid == 0) {
        int c0 = counts[n * 4 + 0], c1 = counts[n * 4 + 1], c2 = counts[n * 4 + 2];
        cur[0] = 0; cur[1] = c0; cur[2] = c0 + c1; cur[3] = c0 + c1 + c2;
        row_base[n * 4 + 0] = cur[0]; row_base[n * 4 + 1] = cur[1];
        row_base[n * 4 + 2] = cur[2]; row_base[n * 4 + 3] = cur[3];
    }
    __syncthreads();
    int e = expert_id[n * 1024 + tid];
    int pos = atomicAdd(&cur[e], 1);
    rows[n * 1024 + pos] = tid;
}

// ---------------------------------------------------------------- grouped GEMM (BM=256, BN templated)
template <int K, int N, int BN, bool GATHER, bool RELU, bool OUTBF>
__global__ __launch_bounds__(512) void moe_gemm_kernel(
    const __bf16* __restrict__ Abase, const float* __restrict__ Bsrc,
    const float* __restrict__ bias, const int* __restrict__ rows_all,
    const int* __restrict__ counts_all, const int* __restrict__ rowbase_all,
    __bf16* __restrict__ outB, float* __restrict__ outF)
{
    constexpr int CQ  = BN / 4;
    constexpr int UB  = BN / 64;
    constexpr int NFR = BN / 32;

    const int gy = blockIdx.y;
    const int mod = gy >> 4, rem = gy & 15;
    const int e = rem >> 2, mt = rem & 3;
    const int grp = mod * 4 + e;
    const int cnt = counts_all[grp];
    const int row0 = mt * 256;
    if (row0 >= cnt) return;
    const int rbase = rowbase_all[grp];
    const int valid = min(256, cnt - row0);
    const int n0 = blockIdx.x * BN;
    const int* rows = rows_all + mod * 1024;

    __shared__ alignas(16) __bf16 As[256 * 64];
    __shared__ alignas(16) __bf16 Bs[BN * 64];

    const int tid = threadIdx.x;
    const int l = tid & 63, w = tid >> 6;
    const int wr = w >> 1, wc = w & 1;

    const __bf16* aptr[4];
    int woffA[4];
    const __bf16* abase2 = GATHER ? Abase : (Abase + (size_t)mod * 1024 * (size_t)K);
    #pragma unroll
    for (int i = 0; i < 4; ++i) {
        int flat = tid + i * 512;
        int rr = flat >> 3, cc = flat & 7;
        int ri = rbase + row0 + min(rr, valid - 1);
        int ga = GATHER ? rows[ri] : ri;
        aptr[i] = abase2 + (size_t)ga * K + cc * 8;
        woffA[i] = rr * 64 + ((cc ^ (rr & 7)) * 8);
    }
    const float* bp0 = Bsrc + (size_t)grp * K * N + n0;
    const float* bptr[UB][2];
    int boff[UB], bx[UB];
    #pragma unroll
    for (int i = 0; i < UB; ++i) {
        int u = tid + i * 512;
        int rp = u / CQ, cq = u % CQ;
        bptr[i][0] = bp0 + (size_t)(2 * rp) * N + 4 * cq;
        bptr[i][1] = bp0 + (size_t)(2 * rp + 1) * N + 4 * cq;
        boff[i] = (4 * cq) * 64 + ((rp & 3) << 1);
        bx[i] = (rp >> 2) ^ (4 * (cq & 1)) ^ ((cq >> 1) & 7);
    }

    f32x4 acc[4][NFR];
    f32x4 zero = {0.f, 0.f, 0.f, 0.f};
    #pragma unroll
    for (int mi = 0; mi < 4; ++mi)
        #pragma unroll
        for (int ni = 0; ni < NFR; ++ni) acc[mi][ni] = zero;

    bf16x8 av[4], avn[4];
    f32x4 bv[UB][2], bvn[UB][2];
    #pragma unroll
    for (int i = 0; i < 4; ++i) av[i] = *(const bf16x8*)aptr[i];
    #pragma unroll
    for (int i = 0; i < UB; ++i) {
        bv[i][0] = *(const f32x4*)bptr[i][0];
        bv[i][1] = *(const f32x4*)bptr[i][1];
    }

    for (int k0 = 0; k0 < K; k0 += 64) {
        __syncthreads();
        #pragma unroll
        for (int i = 0; i < 4; ++i) *(bf16x8*)(As + woffA[i]) = av[i];
        #pragma unroll
        for (int i = 0; i < UB; ++i) {
            #pragma unroll
            for (int qq = 0; qq < 4; ++qq) {
                bf16x2 val = {(__bf16)bv[i][0][qq], (__bf16)bv[i][1][qq]};
                *(bf16x2*)(Bs + boff[i] + qq * 64 + ((bx[i] ^ qq) << 3)) = val;
            }
        }
        if (k0 + 64 < K) {
            #pragma unroll
            for (int i = 0; i < 4; ++i) {
                aptr[i] += 64;
                avn[i] = *(const bf16x8*)aptr[i];
            }
            #pragma unroll
            for (int i = 0; i < UB; ++i) {
                bptr[i][0] += (size_t)64 * N;
                bptr[i][1] += (size_t)64 * N;
                bvn[i][0] = *(const f32x4*)bptr[i][0];
                bvn[i][1] = *(const f32x4*)bptr[i][1];
            }
        }
        __syncthreads();
        #pragma unroll
        for (int kk = 0; kk < 2; ++kk) {
            bf16x8 af[4], bfv[NFR];
            #pragma unroll
            for (int mi = 0; mi < 4; ++mi) {
                int row = wr * 64 + mi * 16 + (l & 15);
                int cc = (kk * 4 + (l >> 4)) ^ (row & 7);
                af[mi] = *(const bf16x8*)(As + row * 64 + cc * 8);
            }
            #pragma unroll
            for (int ni = 0; ni < NFR; ++ni) {
                int nrow = wc * (BN / 2) + ni * 16 + (l & 15);
                int gg = (nrow ^ (nrow >> 3)) & 7;
                int cc = (kk * 4 + (l >> 4)) ^ gg;
                bfv[ni] = *(const bf16x8*)(Bs + nrow * 64 + cc * 8);
            }
            #pragma unroll
            for (int mi = 0; mi < 4; ++mi)
                #pragma unroll
                for (int ni = 0; ni < NFR; ++ni)
                    acc[mi][ni] = __builtin_amdgcn_mfma_f32_16x16x32_bf16(
                        af[mi], bfv[ni], acc[mi][ni], 0, 0, 0);
        }
        #pragma unroll
        for (int i = 0; i < 4; ++i) av[i] = avn[i];
        #pragma unroll
        for (int i = 0; i < UB; ++i) {
            bv[i][0] = bvn[i][0];
            bv[i][1] = bvn[i][1];
        }
    }

    const int lrow = l >> 4, lcol = l & 15;
    #pragma unroll
    for (int ni = 0; ni < NFR; ++ni) {
        int col = n0 + wc * (BN / 2) + ni * 16 + lcol;
        float bval = bias[(size_t)grp * N + col];
        #pragma unroll
        for (int mi = 0; mi < 4; ++mi) {
            #pragma unroll
            for (int j = 0; j < 4; ++j) {
                int rt = wr * 64 + mi * 16 + lrow * 4 + j;
                if (rt < valid) {
                    float v = acc[mi][ni][j] + bval;
                    if (RELU) v = fmaxf(v, 0.f);
                    int crow = rbase + row0 + rt;
                    if (OUTBF) {
                        outB[((size_t)mod * 1024 + crow) * N + col] = (__bf16)v;
                    } else {
                        int tokid = rows[crow];
                        outF[((size_t)mod * 1024 + tokid) * N + col] = v;
                    }
                }
            }
        }
    }
}

// ---------------------------------------------------------------- poly + sigmoid
__global__ __launch_bounds__(256) void poly_kernel(
    const float* __restrict__ input, const float* __restrict__ moe,
    float* __restrict__ out)
{
    const int b = blockIdx.x, tid = threadIdx.x;
    float4 f0 = *(const float4*)(moe + (size_t)(0 * 1024 + b) * 1024 + tid * 4); // transform
    float4 f1 = *(const float4*)(moe + (size_t)(1 * 1024 + b) * 1024 + tid * 4); // add
    float4 f2 = *(const float4*)(moe + (size_t)(2 * 1024 + b) * 1024 + tid * 4); // quad
    float4 f3 = *(const float4*)(moe + (size_t)(3 * 1024 + b) * 1024 + tid * 4); // cubic
    float4 f4 = *(const float4*)(moe + (size_t)(4 * 1024 + b) * 1024 + tid * 4); // fourth
    const float4* ipv = (const float4*)(input + (size_t)b * 10240);
    float4* opv = (float4*)(out + (size_t)b * 10240);
    #pragma unroll
    for (int t = 0; t < 10; ++t) {
        float4 x = ipv[t * 256 + tid];
        float4 r;
        {
            float i2 = x.x * x.x;
            float p = i2 * (i2 * f4.x + x.x * f3.x + f2.x) + x.x * f0.x + f1.x;
            r.x = 1.f / (1.f + __expf(-p));
        }
        {
            float i2 = x.y * x.y;
            float p = i2 * (i2 * f4.y + x.y * f3.y + f2.y) + x.y * f0.y + f1.y;
            r.y = 1.f / (1.f + __expf(-p));
        }
        {
            float i2 = x.z * x.z;
            float p = i2 * (i2 * f4.z + x.z * f3.z + f2.z) + x.z * f0.z + f1.z;
            r.z = 1.f / (1.f + __expf(-p));
        }
        {
            float i2 = x.w * x.w;
            float p = i2 * (i2 * f4.w + x.w * f3.w + f2.w) + x.w * f0.w + f1.w;
            r.w = 1.f / (1.f + __expf(-p));
        }
        opv[t * 256 + tid] = r;
    }
}

// ---------------------------------------------------------------- loss
__global__ void loss_kernel(const int* __restrict__ counts, float* __restrict__ out_loss)
{
    if (threadIdx.x == 0 && blockIdx.x == 0) {
        float total = 0.f;
        for (int n = 0; n < NMOE; ++n) {
            const float m = 256.f;
            float var = 0.f;
            for (int e = 0; e < 4; ++e) {
                float d = (float)counts[n * 4 + e] - m;
                var += d * d;
            }
            var *= (1.f / 3.f);                       // ddof=1
            float cv2 = var / (m * m + 1e-10f);
            total += 2.f * cv2 * 1e-2f;               // importance == load == counts
        }
        *out_loss = total;
    }
}

// ---------------------------------------------------------------- launch
extern "C" void kernel_launch(void* const* d_in, const int* in_sizes, int n_in,
                              void* d_out, int out_size, void* d_ws, size_t ws_size,
                              hipStream_t stream)
{
    (void)in_sizes; (void)n_in; (void)out_size; (void)ws_size;
    const float* input = (const float*)d_in[0];
    const float* c1w   = (const float*)d_in[1];
    const float* c1b   = (const float*)d_in[2];
    const float* c2w   = (const float*)d_in[3];
    const float* c2b   = (const float*)d_in[4];
    const float* wgate = (const float*)d_in[5];
    const float* w1    = (const float*)d_in[6];
    const float* b1    = (const float*)d_in[7];
    const float* w2    = (const float*)d_in[8];
    const float* b2    = (const float*)d_in[9];
    float* out = (float*)d_out;

    char* ws = (char*)d_ws;
    float*  tok_f32   = (float*)(ws + 0);                 //  4 MB
    __bf16* tok_bf16  = (__bf16*)(ws + 4194304);          //  2 MB
    __bf16* h         = (__bf16*)(ws + 6291456);          // 20.97 MB [5][1024][2048] bf16
    float*  moe_out   = (float*)(ws + 27262976);          // 20.97 MB [5][1024][1024] f32
    int*    rows      = (int*)(ws + 48234496);            // [5][1024]
    int*    expert_id = (int*)(ws + 48254976);            // [5][1024]
    int*    counts    = (int*)(ws + 48275456);            // [5][4]
    int*    row_base  = (int*)(ws + 48275536);            // [5][4]

    hipMemsetAsync(counts, 0, NMOE * NEXP * sizeof(int), stream);

    conv_tok_kernel<<<1024, 256, 0, stream>>>(input, c1w, c1b, c2w, c2b, tok_f32, tok_bf16);
    gating_kernel<<<1280, 256, 0, stream>>>(tok_f32, wgate, expert_id, counts);
    scatter_kernel<<<5, 1024, 0, stream>>>(expert_id, counts, row_base, rows);

    moe_gemm_kernel<1024, 2048, 128, true, true, true><<<dim3(16, 80), 512, 0, stream>>>(
        tok_bf16, w1, b1, rows, counts, row_base, h, nullptr);
    moe_gemm_kernel<2048, 1024, 64, false, false, false><<<dim3(16, 80), 512, 0, stream>>>(
        h, w2, b2, rows, counts, row_base, nullptr, moe_out);

    poly_kernel<<<1024, 256, 0, stream>>>(input, moe_out, out);
    loss_kernel<<<1, 64, 0, stream>>>(counts, out + 10485760);
}

// Round 10
// 445.134 us; speedup vs baseline: 3.7393x; 1.1746x over previous
//
#include <hip/hip_runtime.h>
#include <hip/hip_bf16.h>

// ED_Fourth_MOE round 10: revert conv to round-6 verbatim (best proven: 178us,
// conflict-free wcol layout, t-amortized, launch_bounds(256,3)); rounds 7-9's
// vectorization attempts all lost to spill (r7: 2.9GB scratch), localMem (r8:
// 406MB acc spill), or bank conflicts (r9: 73M cycles). GEMMs/gating/scatter
// unchanged (proven). Loss fused into poly (-1 dispatch).

typedef __bf16 bf16x8 __attribute__((ext_vector_type(8)));
typedef __bf16 bf16x4 __attribute__((ext_vector_type(4)));
typedef __bf16 bf16x2 __attribute__((ext_vector_type(2)));
typedef float f32x4 __attribute__((ext_vector_type(4)));

#define NMOE 5
#define NEXP 4

// ---------------------------------------------------------------- conv fused (round-6 verbatim)
__global__ __launch_bounds__(256, 3) void conv_tok_kernel(
    const float* __restrict__ input, const float* __restrict__ c1w,
    const float* __restrict__ c1b, const float* __restrict__ c2w,
    const float* __restrict__ c2b, float* __restrict__ tok_f32,
    __bf16* __restrict__ tok_bf16)
{
    __shared__ float in_s[10][34][34];
    __shared__ float P[34][34];
    const int b = blockIdx.x, tid = threadIdx.x;

    float* ls = &in_s[0][0][0];
    for (int i = tid; i < 10 * 34 * 34; i += 256) ls[i] = 0.f;
    for (int i = tid; i < 34 * 34; i += 256) (&P[0][0])[i] = 0.f;
    __syncthreads();

    const float* ip = input + (size_t)b * 10240;
    for (int i = tid; i < 2560; i += 256) {
        int t = i >> 8, rem = i & 255;
        int h = rem >> 3, w4 = rem & 7;
        float4 v = ((const float4*)ip)[i];
        float* dst = &in_s[t][h + 1][w4 * 4 + 1];
        dst[0] = v.x; dst[1] = v.y; dst[2] = v.z; dst[3] = v.w;
    }
    __syncthreads();

    const int wcol = tid & 31;
    const int r0 = (tid >> 5) * 4;
    const float c2bias = c2b[0];
    float tk0 = c2bias, tk1 = c2bias, tk2 = c2bias, tk3 = c2bias;

    for (int c = 0; c < 10; ++c) {
        float w1l[27];
        #pragma unroll
        for (int i = 0; i < 27; ++i) w1l[i] = c1w[c * 27 + i];
        const float c1bias = c1b[c];

        // 10 live conv1 accumulators per pixel (fully unrolled indices only)
        float a0[10], a1[10], a2[10], a3[10];
        #pragma unroll
        for (int t = 0; t < 10; ++t) {
            a0[t] = c1bias; a1[t] = c1bias; a2[t] = c1bias; a3[t] = c1bias;
        }

        #pragma unroll
        for (int ts = 0; ts < 10; ++ts) {
            // ---- load 6x3 patch of plane ts into registers (read ONCE)
            float p0[3], p1[3], p2[3], p3[3], p4[3], p5[3];
            #pragma unroll
            for (int dw = 0; dw < 3; ++dw) {
                p0[dw] = in_s[ts][r0 + 0][wcol + dw];
                p1[dw] = in_s[ts][r0 + 1][wcol + dw];
                p2[dw] = in_s[ts][r0 + 2][wcol + dw];
                p3[dw] = in_s[ts][r0 + 3][wcol + dw];
                p4[dw] = in_s[ts][r0 + 4][wcol + dw];
                p5[dw] = in_s[ts][r0 + 5][wcol + dw];
            }
            // ---- plane ts feeds: dt=0 -> t=ts+1, dt=1 -> t=ts, dt=2 -> t=ts-1.
            #pragma unroll
            for (int dt = 0; dt < 3; ++dt) {
                const int t = ts - dt + 1;
                if (t < 0 || t > 9) continue;
                #pragma unroll
                for (int dw = 0; dw < 3; ++dw) {
                    float u0 = w1l[dt * 9 + 0 + dw];
                    float u1 = w1l[dt * 9 + 3 + dw];
                    float u2 = w1l[dt * 9 + 6 + dw];
                    a0[t] += u0 * p0[dw] + u1 * p1[dw] + u2 * p2[dw];
                    a1[t] += u0 * p1[dw] + u1 * p2[dw] + u2 * p3[dw];
                    a2[t] += u0 * p2[dw] + u1 * p3[dw] + u2 * p4[dw];
                    a3[t] += u0 * p3[dw] + u1 * p4[dw] + u2 * p5[dw];
                }
            }
            // ---- acc[ts-1] is complete: P write + conv2 (round-1 verbatim)
            if (ts >= 1) {
                const int td = ts - 1;
                __syncthreads();   // previous plane's conv2 reads done
                P[r0 + 1][wcol + 1] = fmaxf(a0[td], 0.f);
                P[r0 + 2][wcol + 1] = fmaxf(a1[td], 0.f);
                P[r0 + 3][wcol + 1] = fmaxf(a2[td], 0.f);
                P[r0 + 4][wcol + 1] = fmaxf(a3[td], 0.f);
                __syncthreads();
                const int wb = (c * 10 + td) * 9;
                #pragma unroll
                for (int dw = 0; dw < 3; ++dw) {
                    float q0 = P[r0 + 0][wcol + dw];
                    float q1 = P[r0 + 1][wcol + dw];
                    float q2 = P[r0 + 2][wcol + dw];
                    float q3 = P[r0 + 3][wcol + dw];
                    float q4 = P[r0 + 4][wcol + dw];
                    float q5 = P[r0 + 5][wcol + dw];
                    float u0 = c2w[wb + 0 + dw];
                    float u1 = c2w[wb + 3 + dw];
                    float u2 = c2w[wb + 6 + dw];
                    tk0 += u0 * q0 + u1 * q1 + u2 * q2;
                    tk1 += u0 * q1 + u1 * q2 + u2 * q3;
                    tk2 += u0 * q2 + u1 * q3 + u2 * q4;
                    tk3 += u0 * q3 + u1 * q4 + u2 * q5;
                }
            }
        }
        // ---- tail: td = 9
        {
            __syncthreads();
            P[r0 + 1][wcol + 1] = fmaxf(a0[9], 0.f);
            P[r0 + 2][wcol + 1] = fmaxf(a1[9], 0.f);
            P[r0 + 3][wcol + 1] = fmaxf(a2[9], 0.f);
            P[r0 + 4][wcol + 1] = fmaxf(a3[9], 0.f);
            __syncthreads();
            const int wb = (c * 10 + 9) * 9;
            #pragma unroll
            for (int dw = 0; dw < 3; ++dw) {
                float q0 = P[r0 + 0][wcol + dw];
                float q1 = P[r0 + 1][wcol + dw];
                float q2 = P[r0 + 2][wcol + dw];
                float q3 = P[r0 + 3][wcol + dw];
                float q4 = P[r0 + 4][wcol + dw];
                float q5 = P[r0 + 5][wcol + dw];
                float u0 = c2w[wb + 0 + dw];
                float u1 = c2w[wb + 3 + dw];
                float u2 = c2w[wb + 6 + dw];
                tk0 += u0 * q0 + u1 * q1 + u2 * q2;
                tk1 += u0 * q1 + u1 * q2 + u2 * q3;
                tk2 += u0 * q2 + u1 * q3 + u2 * q4;
                tk3 += u0 * q3 + u1 * q4 + u2 * q5;
            }
        }
    }
    float o0 = fmaxf(tk0, 0.f), o1 = fmaxf(tk1, 0.f);
    float o2 = fmaxf(tk2, 0.f), o3 = fmaxf(tk3, 0.f);
    size_t base = (size_t)b * 1024 + (size_t)r0 * 32 + wcol;
    tok_f32[base] = o0; tok_f32[base + 32] = o1;
    tok_f32[base + 64] = o2; tok_f32[base + 96] = o3;
    tok_bf16[base] = (__bf16)o0; tok_bf16[base + 32] = (__bf16)o1;
    tok_bf16[base + 64] = (__bf16)o2; tok_bf16[base + 96] = (__bf16)o3;
}

// ---------------------------------------------------------------- gating
__global__ __launch_bounds__(256) void gating_kernel(
    const float* __restrict__ tok, const float* __restrict__ w_gate,
    int* __restrict__ expert_id, int* __restrict__ counts)
{
    int gw = blockIdx.x * 4 + (threadIdx.x >> 6);
    int l = threadIdx.x & 63;
    int n = gw >> 10, b = gw & 1023;
    const float* trow = tok + (size_t)b * 1024;
    const float* wg = w_gate + (size_t)n * 4096;
    float a0 = 0.f, a1 = 0.f, a2 = 0.f, a3 = 0.f;
    #pragma unroll
    for (int i = 0; i < 16; ++i) {
        int d = i * 64 + l;
        float tv = trow[d];
        float4 g4 = *(const float4*)(wg + d * 4);
        a0 += tv * g4.x; a1 += tv * g4.y; a2 += tv * g4.z; a3 += tv * g4.w;
    }
    #pragma unroll
    for (int off = 32; off >= 1; off >>= 1) {
        a0 += __shfl_xor(a0, off);
        a1 += __shfl_xor(a1, off);
        a2 += __shfl_xor(a2, off);
        a3 += __shfl_xor(a3, off);
    }
    if (l == 0) {
        int e = 0; float best = a0;
        if (a1 > best) { best = a1; e = 1; }
        if (a2 > best) { best = a2; e = 2; }
        if (a3 > best) { best = a3; e = 3; }
        expert_id[n * 1024 + b] = e;
        atomicAdd(&counts[n * 4 + e], 1);
    }
}

// ---------------------------------------------------------------- scatter
__global__ __launch_bounds__(1024) void scatter_kernel(
    const int* __restrict__ expert_id, const int* __restrict__ counts,
    int* __restrict__ row_base, int* __restrict__ rows)
{
    __shared__ int cur[4];
    int n = blockIdx.x, tid = threadIdx.x;
    if (tid == 0) {
        int c0 = counts[n * 4 + 0], c1 = counts[n * 4 + 1], c2 = counts[n * 4 + 2];
        cur[0] = 0; cur[1] = c0; cur[2] = c0 + c1; cur[3] = c0 + c1 + c2;
        row_base[n * 4 + 0] = cur[0]; row_base[n * 4 + 1] = cur[1];
        row_base[n * 4 + 2] = cur[2]; row_base[n * 4 + 3] = cur[3];
    }
    __syncthreads();
    int e = expert_id[n * 1024 + tid];
    int pos = atomicAdd(&cur[e], 1);
    rows[n * 1024 + pos] = tid;
}

// ---------------------------------------------------------------- grouped GEMM (BM=256, BN templated)
template <int K, int N, int BN, bool GATHER, bool RELU, bool OUTBF>
__global__ __launch_bounds__(512) void moe_gemm_kernel(
    const __bf16* __restrict__ Abase, const float* __restrict__ Bsrc,
    const float* __restrict__ bias, const int* __restrict__ rows_all,
    const int* __restrict__ counts_all, const int* __restrict__ rowbase_all,
    __bf16* __restrict__ outB, float* __restrict__ outF)
{
    constexpr int CQ  = BN / 4;
    constexpr int UB  = BN / 64;
    constexpr int NFR = BN / 32;

    const int gy = blockIdx.y;
    const int mod = gy >> 4, rem = gy & 15;
    const int e = rem >> 2, mt = rem & 3;
    const int grp = mod * 4 + e;
    const int cnt = counts_all[grp];
    const int row0 = mt * 256;
    if (row0 >= cnt) return;
    const int rbase = rowbase_all[grp];
    const int valid = min(256, cnt - row0);
    const int n0 = blockIdx.x * BN;
    const int* rows = rows_all + mod * 1024;

    __shared__ alignas(16) __bf16 As[256 * 64];
    __shared__ alignas(16) __bf16 Bs[BN * 64];

    const int tid = threadIdx.x;
    const int l = tid & 63, w = tid >> 6;
    const int wr = w >> 1, wc = w & 1;

    const __bf16* aptr[4];
    int woffA[4];
    const __bf16* abase2 = GATHER ? Abase : (Abase + (size_t)mod * 1024 * (size_t)K);
    #pragma unroll
    for (int i = 0; i < 4; ++i) {
        int flat = tid + i * 512;
        int rr = flat >> 3, cc = flat & 7;
        int ri = rbase + row0 + min(rr, valid - 1);
        int ga = GATHER ? rows[ri] : ri;
        aptr[i] = abase2 + (size_t)ga * K + cc * 8;
        woffA[i] = rr * 64 + ((cc ^ (rr & 7)) * 8);
    }
    const float* bp0 = Bsrc + (size_t)grp * K * N + n0;
    const float* bptr[UB][2];
    int boff[UB], bx[UB];
    #pragma unroll
    for (int i = 0; i < UB; ++i) {
        int u = tid + i * 512;
        int rp = u / CQ, cq = u % CQ;
        bptr[i][0] = bp0 + (size_t)(2 * rp) * N + 4 * cq;
        bptr[i][1] = bp0 + (size_t)(2 * rp + 1) * N + 4 * cq;
        boff[i] = (4 * cq) * 64 + ((rp & 3) << 1);
        bx[i] = (rp >> 2) ^ (4 * (cq & 1)) ^ ((cq >> 1) & 7);
    }

    f32x4 acc[4][NFR];
    f32x4 zero = {0.f, 0.f, 0.f, 0.f};
    #pragma unroll
    for (int mi = 0; mi < 4; ++mi)
        #pragma unroll
        for (int ni = 0; ni < NFR; ++ni) acc[mi][ni] = zero;

    bf16x8 av[4], avn[4];
    f32x4 bv[UB][2], bvn[UB][2];
    #pragma unroll
    for (int i = 0; i < 4; ++i) av[i] = *(const bf16x8*)aptr[i];
    #pragma unroll
    for (int i = 0; i < UB; ++i) {
        bv[i][0] = *(const f32x4*)bptr[i][0];
        bv[i][1] = *(const f32x4*)bptr[i][1];
    }

    for (int k0 = 0; k0 < K; k0 += 64) {
        __syncthreads();
        #pragma unroll
        for (int i = 0; i < 4; ++i) *(bf16x8*)(As + woffA[i]) = av[i];
        #pragma unroll
        for (int i = 0; i < UB; ++i) {
            #pragma unroll
            for (int qq = 0; qq < 4; ++qq) {
                bf16x2 val = {(__bf16)bv[i][0][qq], (__bf16)bv[i][1][qq]};
                *(bf16x2*)(Bs + boff[i] + qq * 64 + ((bx[i] ^ qq) << 3)) = val;
            }
        }
        if (k0 + 64 < K) {
            #pragma unroll
            for (int i = 0; i < 4; ++i) {
                aptr[i] += 64;
                avn[i] = *(const bf16x8*)aptr[i];
            }
            #pragma unroll
            for (int i = 0; i < UB; ++i) {
                bptr[i][0] += (size_t)64 * N;
                bptr[i][1] += (size_t)64 * N;
                bvn[i][0] = *(const f32x4*)bptr[i][0];
                bvn[i][1] = *(const f32x4*)bptr[i][1];
            }
        }
        __syncthreads();
        #pragma unroll
        for (int kk = 0; kk < 2; ++kk) {
            bf16x8 af[4], bfv[NFR];
            #pragma unroll
            for (int mi = 0; mi < 4; ++mi) {
                int row = wr * 64 + mi * 16 + (l & 15);
                int cc = (kk * 4 + (l >> 4)) ^ (row & 7);
                af[mi] = *(const bf16x8*)(As + row * 64 + cc * 8);
            }
            #pragma unroll
            for (int ni = 0; ni < NFR; ++ni) {
                int nrow = wc * (BN / 2) + ni * 16 + (l & 15);
                int gg = (nrow ^ (nrow >> 3)) & 7;
                int cc = (kk * 4 + (l >> 4)) ^ gg;
                bfv[ni] = *(const bf16x8*)(Bs + nrow * 64 + cc * 8);
            }
            #pragma unroll
            for (int mi = 0; mi < 4; ++mi)
                #pragma unroll
                for (int ni = 0; ni < NFR; ++ni)
                    acc[mi][ni] = __builtin_amdgcn_mfma_f32_16x16x32_bf16(
                        af[mi], bfv[ni], acc[mi][ni], 0, 0, 0);
        }
        #pragma unroll
        for (int i = 0; i < 4; ++i) av[i] = avn[i];
        #pragma unroll
        for (int i = 0; i < UB; ++i) {
            bv[i][0] = bvn[i][0];
            bv[i][1] = bvn[i][1];
        }
    }

    const int lrow = l >> 4, lcol = l & 15;
    #pragma unroll
    for (int ni = 0; ni < NFR; ++ni) {
        int col = n0 + wc * (BN / 2) + ni * 16 + lcol;
        float bval = bias[(size_t)grp * N + col];
        #pragma unroll
        for (int mi = 0; mi < 4; ++mi) {
            #pragma unroll
            for (int j = 0; j < 4; ++j) {
                int rt = wr * 64 + mi * 16 + lrow * 4 + j;
                if (rt < valid) {
                    float v = acc[mi][ni][j] + bval;
                    if (RELU) v = fmaxf(v, 0.f);
                    int crow = rbase + row0 + rt;
                    if (OUTBF) {
                        outB[((size_t)mod * 1024 + crow) * N + col] = (__bf16)v;
                    } else {
                        int tokid = rows[crow];
                        outF[((size_t)mod * 1024 + tokid) * N + col] = v;
                    }
                }
            }
        }
    }
}

// ---------------------------------------------------------------- poly + sigmoid + loss
__global__ __launch_bounds__(256) void poly_kernel(
    const float* __restrict__ input, const float* __restrict__ moe,
    const int* __restrict__ counts, float* __restrict__ out,
    float* __restrict__ out_loss)
{
    const int b = blockIdx.x, tid = threadIdx.x;
    float4 f0 = *(const float4*)(moe + (size_t)(0 * 1024 + b) * 1024 + tid * 4); // transform
    float4 f1 = *(const float4*)(moe + (size_t)(1 * 1024 + b) * 1024 + tid * 4); // add
    float4 f2 = *(const float4*)(moe + (size_t)(2 * 1024 + b) * 1024 + tid * 4); // quad
    float4 f3 = *(const float4*)(moe + (size_t)(3 * 1024 + b) * 1024 + tid * 4); // cubic
    float4 f4 = *(const float4*)(moe + (size_t)(4 * 1024 + b) * 1024 + tid * 4); // fourth
    const float4* ipv = (const float4*)(input + (size_t)b * 10240);
    float4* opv = (float4*)(out + (size_t)b * 10240);
    #pragma unroll
    for (int t = 0; t < 10; ++t) {
        float4 x = ipv[t * 256 + tid];
        float4 r;
        {
            float i2 = x.x * x.x;
            float p = i2 * (i2 * f4.x + x.x * f3.x + f2.x) + x.x * f0.x + f1.x;
            r.x = 1.f / (1.f + __expf(-p));
        }
        {
            float i2 = x.y * x.y;
            float p = i2 * (i2 * f4.y + x.y * f3.y + f2.y) + x.y * f0.y + f1.y;
            r.y = 1.f / (1.f + __expf(-p));
        }
        {
            float i2 = x.z * x.z;
            float p = i2 * (i2 * f4.z + x.z * f3.z + f2.z) + x.z * f0.z + f1.z;
            r.z = 1.f / (1.f + __expf(-p));
        }
        {
            float i2 = x.w * x.w;
            float p = i2 * (i2 * f4.w + x.w * f3.w + f2.w) + x.w * f0.w + f1.w;
            r.w = 1.f / (1.f + __expf(-p));
        }
        opv[t * 256 + tid] = r;
    }
    // fused loss (counts ready since scatter; importance == load == counts, k=1)
    if (b == 0 && tid == 0) {
        float total = 0.f;
        for (int n = 0; n < NMOE; ++n) {
            const float m = 256.f;
            float var = 0.f;
            for (int e = 0; e < 4; ++e) {
                float d = (float)counts[n * 4 + e] - m;
                var += d * d;
            }
            var *= (1.f / 3.f);                       // ddof=1
            float cv2 = var / (m * m + 1e-10f);
            total += 2.f * cv2 * 1e-2f;
        }
        *out_loss = total;
    }
}

// ---------------------------------------------------------------- launch
extern "C" void kernel_launch(void* const* d_in, const int* in_sizes, int n_in,
                              void* d_out, int out_size, void* d_ws, size_t ws_size,
                              hipStream_t stream)
{
    (void)in_sizes; (void)n_in; (void)out_size; (void)ws_size;
    const float* input = (const float*)d_in[0];
    const float* c1w   = (const float*)d_in[1];
    const float* c1b   = (const float*)d_in[2];
    const float* c2w   = (const float*)d_in[3];
    const float* c2b   = (const float*)d_in[4];
    const float* wgate = (const float*)d_in[5];
    const float* w1    = (const float*)d_in[6];
    const float* b1    = (const float*)d_in[7];
    const float* w2    = (const float*)d_in[8];
    const float* b2    = (const float*)d_in[9];
    float* out = (float*)d_out;

    char* ws = (char*)d_ws;
    float*  tok_f32   = (float*)(ws + 0);                 //  4 MB
    __bf16* tok_bf16  = (__bf16*)(ws + 4194304);          //  2 MB
    __bf16* h         = (__bf16*)(ws + 6291456);          // 20.97 MB [5][1024][2048] bf16
    float*  moe_out   = (float*)(ws + 27262976);          // 20.97 MB [5][1024][1024] f32
    int*    rows      = (int*)(ws + 48234496);            // [5][1024]
    int*    expert_id = (int*)(ws + 48254976);            // [5][1024]
    int*    counts    = (int*)(ws + 48275456);            // [5][4]
    int*    row_base  = (int*)(ws + 48275536);            // [5][4]

    hipMemsetAsync(counts, 0, NMOE * NEXP * sizeof(int), stream);

    conv_tok_kernel<<<1024, 256, 0, stream>>>(input, c1w, c1b, c2w, c2b, tok_f32, tok_bf16);
    gating_kernel<<<1280, 256, 0, stream>>>(tok_f32, wgate, expert_id, counts);
    scatter_kernel<<<5, 1024, 0, stream>>>(expert_id, counts, row_base, rows);

    moe_gemm_kernel<1024, 2048, 128, true, true, true><<<dim3(16, 80), 512, 0, stream>>>(
        tok_bf16, w1, b1, rows, counts, row_base, h, nullptr);
    moe_gemm_kernel<2048, 1024, 64, false, false, false><<<dim3(16, 80), 512, 0, stream>>>(
        h, w2, b2, rows, counts, row_base, nullptr, moe_out);

    poly_kernel<<<1024, 256, 0, stream>>>(input, moe_out, counts, out, out + 10485760);
}

// Round 11
// 398.188 us; speedup vs baseline: 4.1801x; 1.1179x over previous
//
#include <hip/hip_runtime.h>
#include <hip/hip_bf16.h>

// ED_Fourth_MOE round 11:
//  - conv: round-6 verbatim arithmetic (proven 177us, bit-exact tok) + FUSED GATING
//    epilogue: token staged in P-LDS, round-1 gating loop verbatim (same accumulation
//    order, same shfl tree, same argmax) -> expert choice provably identical.
//    tok_f32 global write removed (gating was its only reader).
//  - GEMM1: BN=64 (proven by GEMM2's instantiation) -> 2x blocks, better CU balance,
//    40KB LDS -> 4 blocks/CU. Per-output K-chain unchanged.
//  - scatter/GEMM2/poly+loss: unchanged (proven).

typedef __bf16 bf16x8 __attribute__((ext_vector_type(8)));
typedef __bf16 bf16x4 __attribute__((ext_vector_type(4)));
typedef __bf16 bf16x2 __attribute__((ext_vector_type(2)));
typedef float f32x4 __attribute__((ext_vector_type(4)));

#define NMOE 5
#define NEXP 4

// ---------------------------------------------------------------- conv fused + gating
__global__ __launch_bounds__(256, 3) void conv_tok_kernel(
    const float* __restrict__ input, const float* __restrict__ c1w,
    const float* __restrict__ c1b, const float* __restrict__ c2w,
    const float* __restrict__ c2b, const float* __restrict__ w_gate,
    __bf16* __restrict__ tok_bf16, int* __restrict__ expert_id,
    int* __restrict__ counts)
{
    __shared__ float in_s[10][34][34];
    __shared__ float P[34][34];
    const int b = blockIdx.x, tid = threadIdx.x;

    float* ls = &in_s[0][0][0];
    for (int i = tid; i < 10 * 34 * 34; i += 256) ls[i] = 0.f;
    for (int i = tid; i < 34 * 34; i += 256) (&P[0][0])[i] = 0.f;
    __syncthreads();

    const float* ip = input + (size_t)b * 10240;
    for (int i = tid; i < 2560; i += 256) {
        int t = i >> 8, rem = i & 255;
        int h = rem >> 3, w4 = rem & 7;
        float4 v = ((const float4*)ip)[i];
        float* dst = &in_s[t][h + 1][w4 * 4 + 1];
        dst[0] = v.x; dst[1] = v.y; dst[2] = v.z; dst[3] = v.w;
    }
    __syncthreads();

    const int wcol = tid & 31;
    const int r0 = (tid >> 5) * 4;
    const float c2bias = c2b[0];
    float tk0 = c2bias, tk1 = c2bias, tk2 = c2bias, tk3 = c2bias;

    for (int c = 0; c < 10; ++c) {
        float w1l[27];
        #pragma unroll
        for (int i = 0; i < 27; ++i) w1l[i] = c1w[c * 27 + i];
        const float c1bias = c1b[c];

        // 10 live conv1 accumulators per pixel (fully unrolled indices only)
        float a0[10], a1[10], a2[10], a3[10];
        #pragma unroll
        for (int t = 0; t < 10; ++t) {
            a0[t] = c1bias; a1[t] = c1bias; a2[t] = c1bias; a3[t] = c1bias;
        }

        #pragma unroll
        for (int ts = 0; ts < 10; ++ts) {
            // ---- load 6x3 patch of plane ts into registers (read ONCE)
            float p0[3], p1[3], p2[3], p3[3], p4[3], p5[3];
            #pragma unroll
            for (int dw = 0; dw < 3; ++dw) {
                p0[dw] = in_s[ts][r0 + 0][wcol + dw];
                p1[dw] = in_s[ts][r0 + 1][wcol + dw];
                p2[dw] = in_s[ts][r0 + 2][wcol + dw];
                p3[dw] = in_s[ts][r0 + 3][wcol + dw];
                p4[dw] = in_s[ts][r0 + 4][wcol + dw];
                p5[dw] = in_s[ts][r0 + 5][wcol + dw];
            }
            // ---- plane ts feeds: dt=0 -> t=ts+1, dt=1 -> t=ts, dt=2 -> t=ts-1.
            #pragma unroll
            for (int dt = 0; dt < 3; ++dt) {
                const int t = ts - dt + 1;
                if (t < 0 || t > 9) continue;
                #pragma unroll
                for (int dw = 0; dw < 3; ++dw) {
                    float u0 = w1l[dt * 9 + 0 + dw];
                    float u1 = w1l[dt * 9 + 3 + dw];
                    float u2 = w1l[dt * 9 + 6 + dw];
                    a0[t] += u0 * p0[dw] + u1 * p1[dw] + u2 * p2[dw];
                    a1[t] += u0 * p1[dw] + u1 * p2[dw] + u2 * p3[dw];
                    a2[t] += u0 * p2[dw] + u1 * p3[dw] + u2 * p4[dw];
                    a3[t] += u0 * p3[dw] + u1 * p4[dw] + u2 * p5[dw];
                }
            }
            // ---- acc[ts-1] is complete: P write + conv2 (round-1 verbatim)
            if (ts >= 1) {
                const int td = ts - 1;
                __syncthreads();   // previous plane's conv2 reads done
                P[r0 + 1][wcol + 1] = fmaxf(a0[td], 0.f);
                P[r0 + 2][wcol + 1] = fmaxf(a1[td], 0.f);
                P[r0 + 3][wcol + 1] = fmaxf(a2[td], 0.f);
                P[r0 + 4][wcol + 1] = fmaxf(a3[td], 0.f);
                __syncthreads();
                const int wb = (c * 10 + td) * 9;
                #pragma unroll
                for (int dw = 0; dw < 3; ++dw) {
                    float q0 = P[r0 + 0][wcol + dw];
                    float q1 = P[r0 + 1][wcol + dw];
                    float q2 = P[r0 + 2][wcol + dw];
                    float q3 = P[r0 + 3][wcol + dw];
                    float q4 = P[r0 + 4][wcol + dw];
                    float q5 = P[r0 + 5][wcol + dw];
                    float u0 = c2w[wb + 0 + dw];
                    float u1 = c2w[wb + 3 + dw];
                    float u2 = c2w[wb + 6 + dw];
                    tk0 += u0 * q0 + u1 * q1 + u2 * q2;
                    tk1 += u0 * q1 + u1 * q2 + u2 * q3;
                    tk2 += u0 * q2 + u1 * q3 + u2 * q4;
                    tk3 += u0 * q3 + u1 * q4 + u2 * q5;
                }
            }
        }
        // ---- tail: td = 9
        {
            __syncthreads();
            P[r0 + 1][wcol + 1] = fmaxf(a0[9], 0.f);
            P[r0 + 2][wcol + 1] = fmaxf(a1[9], 0.f);
            P[r0 + 3][wcol + 1] = fmaxf(a2[9], 0.f);
            P[r0 + 4][wcol + 1] = fmaxf(a3[9], 0.f);
            __syncthreads();
            const int wb = (c * 10 + 9) * 9;
            #pragma unroll
            for (int dw = 0; dw < 3; ++dw) {
                float q0 = P[r0 + 0][wcol + dw];
                float q1 = P[r0 + 1][wcol + dw];
                float q2 = P[r0 + 2][wcol + dw];
                float q3 = P[r0 + 3][wcol + dw];
                float q4 = P[r0 + 4][wcol + dw];
                float q5 = P[r0 + 5][wcol + dw];
                float u0 = c2w[wb + 0 + dw];
                float u1 = c2w[wb + 3 + dw];
                float u2 = c2w[wb + 6 + dw];
                tk0 += u0 * q0 + u1 * q1 + u2 * q2;
                tk1 += u0 * q1 + u1 * q2 + u2 * q3;
                tk2 += u0 * q2 + u1 * q3 + u2 * q4;
                tk3 += u0 * q3 + u1 * q4 + u2 * q5;
            }
        }
    }
    float o0 = fmaxf(tk0, 0.f), o1 = fmaxf(tk1, 0.f);
    float o2 = fmaxf(tk2, 0.f), o3 = fmaxf(tk3, 0.f);
    size_t base = (size_t)b * 1024 + (size_t)r0 * 32 + wcol;
    tok_bf16[base] = (__bf16)o0; tok_bf16[base + 32] = (__bf16)o1;
    tok_bf16[base + 64] = (__bf16)o2; tok_bf16[base + 96] = (__bf16)o3;

    // ---------------- fused gating (round-1 kernel verbatim, tok via LDS) ----------------
    __syncthreads();                       // all conv2 P reads done; P is free
    float* tokLDS = &P[0][0];              // 1024 floats fit in 34*34
    tokLDS[(r0 + 0) * 32 + wcol] = o0;
    tokLDS[(r0 + 1) * 32 + wcol] = o1;
    tokLDS[(r0 + 2) * 32 + wcol] = o2;
    tokLDS[(r0 + 3) * 32 + wcol] = o3;
    __syncthreads();

    const int l = tid & 63, w = tid >> 6;
    for (int n = w; n < NMOE; n += 4) {
        const float* wg = w_gate + (size_t)n * 4096;
        float a0 = 0.f, a1 = 0.f, a2 = 0.f, a3 = 0.f;
        #pragma unroll
        for (int i = 0; i < 16; ++i) {
            int d = i * 64 + l;
            float tv = tokLDS[d];          // bit-identical to tok_f32[b][d]
            float4 g4 = *(const float4*)(wg + d * 4);
            a0 += tv * g4.x; a1 += tv * g4.y; a2 += tv * g4.z; a3 += tv * g4.w;
        }
        #pragma unroll
        for (int off = 32; off >= 1; off >>= 1) {
            a0 += __shfl_xor(a0, off);
            a1 += __shfl_xor(a1, off);
            a2 += __shfl_xor(a2, off);
            a3 += __shfl_xor(a3, off);
        }
        if (l == 0) {
            int e = 0; float best = a0;
            if (a1 > best) { best = a1; e = 1; }
            if (a2 > best) { best = a2; e = 2; }
            if (a3 > best) { best = a3; e = 3; }
            expert_id[n * 1024 + b] = e;
            atomicAdd(&counts[n * 4 + e], 1);
        }
    }
}

// ---------------------------------------------------------------- scatter
__global__ __launch_bounds__(1024) void scatter_kernel(
    const int* __restrict__ expert_id, const int* __restrict__ counts,
    int* __restrict__ row_base, int* __restrict__ rows)
{
    __shared__ int cur[4];
    int n = blockIdx.x, tid = threadIdx.x;
    if (tid == 0) {
        int c0 = counts[n * 4 + 0], c1 = counts[n * 4 + 1], c2 = counts[n * 4 + 2];
        cur[0] = 0; cur[1] = c0; cur[2] = c0 + c1; cur[3] = c0 + c1 + c2;
        row_base[n * 4 + 0] = cur[0]; row_base[n * 4 + 1] = cur[1];
        row_base[n * 4 + 2] = cur[2]; row_base[n * 4 + 3] = cur[3];
    }
    __syncthreads();
    int e = expert_id[n * 1024 + tid];
    int pos = atomicAdd(&cur[e], 1);
    rows[n * 1024 + pos] = tid;
}

// ---------------------------------------------------------------- grouped GEMM (BM=256, BN templated)
template <int K, int N, int BN, bool GATHER, bool RELU, bool OUTBF>
__global__ __launch_bounds__(512) void moe_gemm_kernel(
    const __bf16* __restrict__ Abase, const float* __restrict__ Bsrc,
    const float* __restrict__ bias, const int* __restrict__ rows_all,
    const int* __restrict__ counts_all, const int* __restrict__ rowbase_all,
    __bf16* __restrict__ outB, float* __restrict__ outF)
{
    constexpr int CQ  = BN / 4;
    constexpr int UB  = BN / 64;
    constexpr int NFR = BN / 32;

    const int gy = blockIdx.y;
    const int mod = gy >> 4, rem = gy & 15;
    const int e = rem >> 2, mt = rem & 3;
    const int grp = mod * 4 + e;
    const int cnt = counts_all[grp];
    const int row0 = mt * 256;
    if (row0 >= cnt) return;
    const int rbase = rowbase_all[grp];
    const int valid = min(256, cnt - row0);
    const int n0 = blockIdx.x * BN;
    const int* rows = rows_all + mod * 1024;

    __shared__ alignas(16) __bf16 As[256 * 64];
    __shared__ alignas(16) __bf16 Bs[BN * 64];

    const int tid = threadIdx.x;
    const int l = tid & 63, w = tid >> 6;
    const int wr = w >> 1, wc = w & 1;

    const __bf16* aptr[4];
    int woffA[4];
    const __bf16* abase2 = GATHER ? Abase : (Abase + (size_t)mod * 1024 * (size_t)K);
    #pragma unroll
    for (int i = 0; i < 4; ++i) {
        int flat = tid + i * 512;
        int rr = flat >> 3, cc = flat & 7;
        int ri = rbase + row0 + min(rr, valid - 1);
        int ga = GATHER ? rows[ri] : ri;
        aptr[i] = abase2 + (size_t)ga * K + cc * 8;
        woffA[i] = rr * 64 + ((cc ^ (rr & 7)) * 8);
    }
    const float* bp0 = Bsrc + (size_t)grp * K * N + n0;
    const float* bptr[UB][2];
    int boff[UB], bx[UB];
    #pragma unroll
    for (int i = 0; i < UB; ++i) {
        int u = tid + i * 512;
        int rp = u / CQ, cq = u % CQ;
        bptr[i][0] = bp0 + (size_t)(2 * rp) * N + 4 * cq;
        bptr[i][1] = bp0 + (size_t)(2 * rp + 1) * N + 4 * cq;
        boff[i] = (4 * cq) * 64 + ((rp & 3) << 1);
        bx[i] = (rp >> 2) ^ (4 * (cq & 1)) ^ ((cq >> 1) & 7);
    }

    f32x4 acc[4][NFR];
    f32x4 zero = {0.f, 0.f, 0.f, 0.f};
    #pragma unroll
    for (int mi = 0; mi < 4; ++mi)
        #pragma unroll
        for (int ni = 0; ni < NFR; ++ni) acc[mi][ni] = zero;

    bf16x8 av[4], avn[4];
    f32x4 bv[UB][2], bvn[UB][2];
    #pragma unroll
    for (int i = 0; i < 4; ++i) av[i] = *(const bf16x8*)aptr[i];
    #pragma unroll
    for (int i = 0; i < UB; ++i) {
        bv[i][0] = *(const f32x4*)bptr[i][0];
        bv[i][1] = *(const f32x4*)bptr[i][1];
    }

    for (int k0 = 0; k0 < K; k0 += 64) {
        __syncthreads();
        #pragma unroll
        for (int i = 0; i < 4; ++i) *(bf16x8*)(As + woffA[i]) = av[i];
        #pragma unroll
        for (int i = 0; i < UB; ++i) {
            #pragma unroll
            for (int qq = 0; qq < 4; ++qq) {
                bf16x2 val = {(__bf16)bv[i][0][qq], (__bf16)bv[i][1][qq]};
                *(bf16x2*)(Bs + boff[i] + qq * 64 + ((bx[i] ^ qq) << 3)) = val;
            }
        }
        if (k0 + 64 < K) {
            #pragma unroll
            for (int i = 0; i < 4; ++i) {
                aptr[i] += 64;
                avn[i] = *(const bf16x8*)aptr[i];
            }
            #pragma unroll
            for (int i = 0; i < UB; ++i) {
                bptr[i][0] += (size_t)64 * N;
                bptr[i][1] += (size_t)64 * N;
                bvn[i][0] = *(const f32x4*)bptr[i][0];
                bvn[i][1] = *(const f32x4*)bptr[i][1];
            }
        }
        __syncthreads();
        #pragma unroll
        for (int kk = 0; kk < 2; ++kk) {
            bf16x8 af[4], bfv[NFR];
            #pragma unroll
            for (int mi = 0; mi < 4; ++mi) {
                int row = wr * 64 + mi * 16 + (l & 15);
                int cc = (kk * 4 + (l >> 4)) ^ (row & 7);
                af[mi] = *(const bf16x8*)(As + row * 64 + cc * 8);
            }
            #pragma unroll
            for (int ni = 0; ni < NFR; ++ni) {
                int nrow = wc * (BN / 2) + ni * 16 + (l & 15);
                int gg = (nrow ^ (nrow >> 3)) & 7;
                int cc = (kk * 4 + (l >> 4)) ^ gg;
                bfv[ni] = *(const bf16x8*)(Bs + nrow * 64 + cc * 8);
            }
            #pragma unroll
            for (int mi = 0; mi < 4; ++mi)
                #pragma unroll
                for (int ni = 0; ni < NFR; ++ni)
                    acc[mi][ni] = __builtin_amdgcn_mfma_f32_16x16x32_bf16(
                        af[mi], bfv[ni], acc[mi][ni], 0, 0, 0);
        }
        #pragma unroll
        for (int i = 0; i < 4; ++i) av[i] = avn[i];
        #pragma unroll
        for (int i = 0; i < UB; ++i) {
            bv[i][0] = bvn[i][0];
            bv[i][1] = bvn[i][1];
        }
    }

    const int lrow = l >> 4, lcol = l & 15;
    #pragma unroll
    for (int ni = 0; ni < NFR; ++ni) {
        int col = n0 + wc * (BN / 2) + ni * 16 + lcol;
        float bval = bias[(size_t)grp * N + col];
        #pragma unroll
        for (int mi = 0; mi < 4; ++mi) {
            #pragma unroll
            for (int j = 0; j < 4; ++j) {
                int rt = wr * 64 + mi * 16 + lrow * 4 + j;
                if (rt < valid) {
                    float v = acc[mi][ni][j] + bval;
                    if (RELU) v = fmaxf(v, 0.f);
                    int crow = rbase + row0 + rt;
                    if (OUTBF) {
                        outB[((size_t)mod * 1024 + crow) * N + col] = (__bf16)v;
                    } else {
                        int tokid = rows[crow];
                        outF[((size_t)mod * 1024 + tokid) * N + col] = v;
                    }
                }
            }
        }
    }
}

// ---------------------------------------------------------------- poly + sigmoid + loss
__global__ __launch_bounds__(256) void poly_kernel(
    const float* __restrict__ input, const float* __restrict__ moe,
    const int* __restrict__ counts, float* __restrict__ out,
    float* __restrict__ out_loss)
{
    const int b = blockIdx.x, tid = threadIdx.x;
    float4 f0 = *(const float4*)(moe + (size_t)(0 * 1024 + b) * 1024 + tid * 4); // transform
    float4 f1 = *(const float4*)(moe + (size_t)(1 * 1024 + b) * 1024 + tid * 4); // add
    float4 f2 = *(const float4*)(moe + (size_t)(2 * 1024 + b) * 1024 + tid * 4); // quad
    float4 f3 = *(const float4*)(moe + (size_t)(3 * 1024 + b) * 1024 + tid * 4); // cubic
    float4 f4 = *(const float4*)(moe + (size_t)(4 * 1024 + b) * 1024 + tid * 4); // fourth
    const float4* ipv = (const float4*)(input + (size_t)b * 10240);
    float4* opv = (float4*)(out + (size_t)b * 10240);
    #pragma unroll
    for (int t = 0; t < 10; ++t) {
        float4 x = ipv[t * 256 + tid];
        float4 r;
        {
            float i2 = x.x * x.x;
            float p = i2 * (i2 * f4.x + x.x * f3.x + f2.x) + x.x * f0.x + f1.x;
            r.x = 1.f / (1.f + __expf(-p));
        }
        {
            float i2 = x.y * x.y;
            float p = i2 * (i2 * f4.y + x.y * f3.y + f2.y) + x.y * f0.y + f1.y;
            r.y = 1.f / (1.f + __expf(-p));
        }
        {
            float i2 = x.z * x.z;
            float p = i2 * (i2 * f4.z + x.z * f3.z + f2.z) + x.z * f0.z + f1.z;
            r.z = 1.f / (1.f + __expf(-p));
        }
        {
            float i2 = x.w * x.w;
            float p = i2 * (i2 * f4.w + x.w * f3.w + f2.w) + x.w * f0.w + f1.w;
            r.w = 1.f / (1.f + __expf(-p));
        }
        opv[t * 256 + tid] = r;
    }
    // fused loss (importance == load == counts, k=1)
    if (b == 0 && tid == 0) {
        float total = 0.f;
        for (int n = 0; n < NMOE; ++n) {
            const float m = 256.f;
            float var = 0.f;
            for (int e = 0; e < 4; ++e) {
                float d = (float)counts[n * 4 + e] - m;
                var += d * d;
            }
            var *= (1.f / 3.f);                       // ddof=1
            float cv2 = var / (m * m + 1e-10f);
            total += 2.f * cv2 * 1e-2f;
        }
        *out_loss = total;
    }
}

// ---------------------------------------------------------------- launch
extern "C" void kernel_launch(void* const* d_in, const int* in_sizes, int n_in,
                              void* d_out, int out_size, void* d_ws, size_t ws_size,
                              hipStream_t stream)
{
    (void)in_sizes; (void)n_in; (void)out_size; (void)ws_size;
    const float* input = (const float*)d_in[0];
    const float* c1w   = (const float*)d_in[1];
    const float* c1b   = (const float*)d_in[2];
    const float* c2w   = (const float*)d_in[3];
    const float* c2b   = (const float*)d_in[4];
    const float* wgate = (const float*)d_in[5];
    const float* w1    = (const float*)d_in[6];
    const float* b1    = (const float*)d_in[7];
    const float* w2    = (const float*)d_in[8];
    const float* b2    = (const float*)d_in[9];
    float* out = (float*)d_out;

    char* ws = (char*)d_ws;
    __bf16* tok_bf16  = (__bf16*)(ws + 4194304);          //  2 MB
    __bf16* h         = (__bf16*)(ws + 6291456);          // 20.97 MB [5][1024][2048] bf16
    float*  moe_out   = (float*)(ws + 27262976);          // 20.97 MB [5][1024][1024] f32
    int*    rows      = (int*)(ws + 48234496);            // [5][1024]
    int*    expert_id = (int*)(ws + 48254976);            // [5][1024]
    int*    counts    = (int*)(ws + 48275456);            // [5][4]
    int*    row_base  = (int*)(ws + 48275536);            // [5][4]

    hipMemsetAsync(counts, 0, NMOE * NEXP * sizeof(int), stream);

    conv_tok_kernel<<<1024, 256, 0, stream>>>(input, c1w, c1b, c2w, c2b, wgate,
                                              tok_bf16, expert_id, counts);
    scatter_kernel<<<5, 1024, 0, stream>>>(expert_id, counts, row_base, rows);

    moe_gemm_kernel<1024, 2048, 64, true, true, true><<<dim3(32, 80), 512, 0, stream>>>(
        tok_bf16, w1, b1, rows, counts, row_base, h, nullptr);
    moe_gemm_kernel<2048, 1024, 64, false, false, false><<<dim3(16, 80), 512, 0, stream>>>(
        h, w2, b2, rows, counts, row_base, nullptr, moe_out);

    poly_kernel<<<1024, 256, 0, stream>>>(input, moe_out, counts, out, out + 10485760);
}